// Round 7
// baseline (347.367 us; speedup 1.0000x reference)
//
#include <hip/hip_runtime.h>
#include <hip/hip_bf16.h>

typedef __bf16 bf16;
typedef __attribute__((ext_vector_type(8))) __bf16 bf16x8;
typedef __attribute__((ext_vector_type(4))) __bf16 bf16x4;
typedef __attribute__((ext_vector_type(4))) float f32x4;

// Problem constants
#define BB 2
#define SS 2048
#define HH 2048
#define NH 16
#define HD 128

#define GLOAD_LDS16(g, l)                                                  \
    __builtin_amdgcn_global_load_lds(                                      \
        (const __attribute__((address_space(1))) void*)(g),                \
        (__attribute__((address_space(3))) void*)(l), 16, 0, 0)

// ---------------------------------------------------------------------------
// Batched fp32 -> bf16 cast: X then Wq,Wk,Wv (into contiguous Wqkv), Wo.
// ---------------------------------------------------------------------------
__global__ __launch_bounds__(256) void cast_all(const float* __restrict__ hs,
                                                const float* __restrict__ Wq,
                                                const float* __restrict__ Wk,
                                                const float* __restrict__ Wv,
                                                const float* __restrict__ Wo,
                                                bf16* __restrict__ Xb,
                                                bf16* __restrict__ Wqkv,
                                                bf16* __restrict__ Wob) {
    const int XE4 = (BB * SS * HH) / 4;
    const int WE4 = (HH * HH) / 4;
    int i = blockIdx.x * 256 + threadIdx.x;
    const float* src;
    bf16* dst;
    int off;
    if (i < XE4) { src = hs; dst = Xb; off = i; }
    else if (i < XE4 + WE4) { src = Wq; dst = Wqkv; off = i - XE4; }
    else if (i < XE4 + 2 * WE4) { src = Wk; dst = Wqkv + (size_t)HH * HH; off = i - XE4 - WE4; }
    else if (i < XE4 + 3 * WE4) { src = Wv; dst = Wqkv + 2 * (size_t)HH * HH; off = i - XE4 - 2 * WE4; }
    else { src = Wo; dst = Wob; off = i - XE4 - 3 * WE4; }
    f32x4 v = *reinterpret_cast<const f32x4*>(src + (size_t)off * 4);
    bf16x4 o;
    o[0] = (bf16)v[0]; o[1] = (bf16)v[1]; o[2] = (bf16)v[2]; o[3] = (bf16)v[3];
    *reinterpret_cast<bf16x4*>(dst + (size_t)off * 4) = o;
}

// ---------------------------------------------------------------------------
// 256x256-tile 8-phase GEMM (R5 version — 131 µs, 0 bank conflicts measured).
// ---------------------------------------------------------------------------
__global__ __launch_bounds__(512, 2) void gemm256_qkv(const bf16* __restrict__ A,
                                                      const bf16* __restrict__ B,
                                                      bf16* __restrict__ Cb,
                                                      int M, int N, int K) {
    __shared__ bf16 LA[2][256 * 64];
    __shared__ bf16 LB[2][256 * 64];
    const int tid = threadIdx.x, lane = tid & 63, wave = tid >> 6;
    const int l15 = lane & 15, lhi = lane >> 4;
    const int wr = wave >> 2, wc = wave & 3;
    const int NBX = N >> 8;
    const int cpx = gridDim.x >> 3;
    const int wg = (blockIdx.x & 7) * cpx + (blockIdx.x >> 3);
    const int m0 = (wg / NBX) * 256, n0 = (wg % NBX) * 256;
    const int NK = K >> 6;
    const int xorR = (l15 & 7) << 4;

    auto stageA = [&](int buf, int t, int h) {
        const int k0 = t << 6;
#pragma unroll
        for (int j = 0; j < 2; ++j) {
            int Xw = ((j * 128 + h * 64) << 7) + (wave << 10);
            int X = Xw + lane * 16;
            int T = X ^ (((X >> 7) & 7) << 4);
            GLOAD_LDS16(&A[(size_t)(m0 + (T >> 7)) * K + k0 + ((T & 127) >> 1)],
                        (char*)LA[buf] + Xw);
        }
    };
    auto stageB = [&](int buf, int t, int h) {
        const int k0 = t << 6;
#pragma unroll
        for (int j = 0; j < 2; ++j) {
            int base_row = h * 32 + (2 * j + (wave >> 2)) * 64;
            int Xw = (base_row << 7) + ((wave & 3) << 10);
            int X = Xw + lane * 16;
            int T = X ^ (((X >> 7) & 7) << 4);
            GLOAD_LDS16(&B[(size_t)(n0 + (T >> 7)) * K + k0 + ((T & 127) >> 1)],
                        (char*)LB[buf] + Xw);
        }
    };

    f32x4 acc[8][4] = {};

    stageA(0, 0, 0); stageB(0, 0, 0); stageB(0, 0, 1); stageA(0, 0, 1);
    stageA(1, 1, 0); stageB(1, 1, 1);
    asm volatile("s_waitcnt vmcnt(4)" ::: "memory");
    __builtin_amdgcn_s_barrier();

    bf16x8 af[4][2], bv0[2][2], bv1[2][2];

#pragma unroll 1
    for (int t = 0; t < NK; ++t) {
        const int buf = t & 1;
        char* lA = (char*)LA[buf];
        char* lB = (char*)LB[buf];

        // q0: (0,0); read A0(8)+B0(4); stage B0(t+1)
#pragma unroll
        for (int f = 0; f < 4; ++f)
#pragma unroll
            for (int ks = 0; ks < 2; ++ks) {
                int T = ((wr * 128 + f * 16 + l15) << 7) + ks * 64 + lhi * 16;
                af[f][ks] = *reinterpret_cast<const bf16x8*>(lA + (T ^ xorR));
            }
#pragma unroll
        for (int g = 0; g < 2; ++g)
#pragma unroll
            for (int ks = 0; ks < 2; ++ks) {
                int T = ((wc * 64 + g * 16 + l15) << 7) + ks * 64 + lhi * 16;
                bv0[g][ks] = *reinterpret_cast<const bf16x8*>(lB + (T ^ xorR));
            }
        if (t + 1 < NK) stageB(buf ^ 1, t + 1, 0);
        __builtin_amdgcn_s_barrier();
        asm volatile("s_waitcnt lgkmcnt(0)" ::: "memory");
        __builtin_amdgcn_s_setprio(1);
#pragma unroll
        for (int f = 0; f < 4; ++f)
#pragma unroll
            for (int g = 0; g < 2; ++g)
#pragma unroll
                for (int ks = 0; ks < 2; ++ks)
                    acc[f][g] = __builtin_amdgcn_mfma_f32_16x16x32_bf16(af[f][ks], bv0[g][ks], acc[f][g], 0, 0, 0);
        __builtin_amdgcn_s_setprio(0);
        __builtin_amdgcn_s_barrier();

        // q1: (0,1); read B1(4); stage A1(t+1)
#pragma unroll
        for (int g = 0; g < 2; ++g)
#pragma unroll
            for (int ks = 0; ks < 2; ++ks) {
                int T = ((wc * 64 + 32 + g * 16 + l15) << 7) + ks * 64 + lhi * 16;
                bv1[g][ks] = *reinterpret_cast<const bf16x8*>(lB + (T ^ xorR));
            }
        if (t + 1 < NK) stageA(buf ^ 1, t + 1, 1);
        __builtin_amdgcn_s_barrier();
        asm volatile("s_waitcnt lgkmcnt(0)" ::: "memory");
        __builtin_amdgcn_s_setprio(1);
#pragma unroll
        for (int f = 0; f < 4; ++f)
#pragma unroll
            for (int g = 0; g < 2; ++g)
#pragma unroll
                for (int ks = 0; ks < 2; ++ks)
                    acc[f][2 + g] = __builtin_amdgcn_mfma_f32_16x16x32_bf16(af[f][ks], bv1[g][ks], acc[f][2 + g], 0, 0, 0);
        __builtin_amdgcn_s_setprio(0);
        __builtin_amdgcn_s_barrier();

        // q2: (1,1); read A1(8); stage A0(t+2)
#pragma unroll
        for (int f = 0; f < 4; ++f)
#pragma unroll
            for (int ks = 0; ks < 2; ++ks) {
                int T = ((wr * 128 + 64 + f * 16 + l15) << 7) + ks * 64 + lhi * 16;
                af[f][ks] = *reinterpret_cast<const bf16x8*>(lA + (T ^ xorR));
            }
        if (t + 2 < NK) stageA(buf, t + 2, 0);
        __builtin_amdgcn_s_barrier();
        asm volatile("s_waitcnt lgkmcnt(0)" ::: "memory");
        __builtin_amdgcn_s_setprio(1);
#pragma unroll
        for (int f = 0; f < 4; ++f)
#pragma unroll
            for (int g = 0; g < 2; ++g)
#pragma unroll
                for (int ks = 0; ks < 2; ++ks)
                    acc[4 + f][2 + g] = __builtin_amdgcn_mfma_f32_16x16x32_bf16(af[f][ks], bv1[g][ks], acc[4 + f][2 + g], 0, 0, 0);
        __builtin_amdgcn_s_setprio(0);
        __builtin_amdgcn_s_barrier();

        // q3: (1,0); no reads; stage B1(t+2)
        if (t + 2 < NK) stageB(buf, t + 2, 1);
        __builtin_amdgcn_s_barrier();
        __builtin_amdgcn_s_setprio(1);
#pragma unroll
        for (int f = 0; f < 4; ++f)
#pragma unroll
            for (int g = 0; g < 2; ++g)
#pragma unroll
                for (int ks = 0; ks < 2; ++ks)
                    acc[4 + f][g] = __builtin_amdgcn_mfma_f32_16x16x32_bf16(af[f][ks], bv0[g][ks], acc[4 + f][g], 0, 0, 0);
        __builtin_amdgcn_s_setprio(0);
        if (t + 2 == NK) {
            asm volatile("s_waitcnt vmcnt(0)" ::: "memory");
        } else if (t + 1 < NK) {
            asm volatile("s_waitcnt vmcnt(4)" ::: "memory");
        }
        __builtin_amdgcn_s_barrier();
    }

#pragma unroll
    for (int mf = 0; mf < 8; ++mf)
#pragma unroll
        for (int nf = 0; nf < 4; ++nf)
#pragma unroll
            for (int r = 0; r < 4; ++r) {
                int gm = m0 + wr * 128 + mf * 16 + lhi * 4 + r;
                int gn = n0 + wc * 64 + nf * 16 + l15;
                int proj = gn >> 11, n2 = gn & 2047;
                int b = gm >> 11, s = gm & (SS - 1);
                int h = n2 >> 7, d = n2 & (HD - 1);
                Cb[((size_t)proj << 23) + ((((size_t)(b * NH + h)) * SS + s) << 7) + d] =
                    (bf16)acc[mf][nf][r];
            }
}

// ---------------------------------------------------------------------------
// 128x128 GEMM (m97 structure), fp32 row-major epilogue (out projection)
// ---------------------------------------------------------------------------
__global__ __launch_bounds__(256) void gemm_bt(const bf16* __restrict__ A,
                                               const bf16* __restrict__ B,
                                               float* __restrict__ Cf,
                                               int M, int N, int K) {
    __shared__ bf16 As[128 * 64];
    __shared__ bf16 Bs[128 * 64];
    const int tid = threadIdx.x;
    const int lane = tid & 63, wave = tid >> 6;
    const int l15 = lane & 15, lhi = lane >> 4;
    const int m0 = blockIdx.y * 128, n0 = blockIdx.x * 128;
    const int wm = (wave >> 1) * 64, wn = (wave & 1) * 64;
    const int lrow = lane >> 3;
    const int lcol = (lane & 7) * 8;

    f32x4 acc[4][4] = {};

    for (int k0 = 0; k0 < K; k0 += 64) {
#pragma unroll
        for (int j = 0; j < 4; ++j) {
            const int c = wave * 4 + j;
            const int row = c * 8 + lrow;
            GLOAD_LDS16(&A[(size_t)(m0 + row) * K + k0 + lcol], &As[c * 512]);
            GLOAD_LDS16(&B[(size_t)(n0 + row) * K + k0 + lcol], &Bs[c * 512]);
        }
        __syncthreads();
#pragma unroll
        for (int ks = 0; ks < 2; ++ks) {
            bf16x8 af[4], bfr[4];
#pragma unroll
            for (int i = 0; i < 4; ++i)
                af[i] = *reinterpret_cast<const bf16x8*>(&As[(wm + i * 16 + l15) * 64 + ks * 32 + 8 * lhi]);
#pragma unroll
            for (int j = 0; j < 4; ++j)
                bfr[j] = *reinterpret_cast<const bf16x8*>(&Bs[(wn + j * 16 + l15) * 64 + ks * 32 + 8 * lhi]);
#pragma unroll
            for (int i = 0; i < 4; ++i)
#pragma unroll
                for (int j = 0; j < 4; ++j)
                    acc[i][j] = __builtin_amdgcn_mfma_f32_16x16x32_bf16(af[i], bfr[j], acc[i][j], 0, 0, 0);
        }
        __syncthreads();
    }

#pragma unroll
    for (int i = 0; i < 4; ++i)
#pragma unroll
        for (int j = 0; j < 4; ++j)
#pragma unroll
            for (int r = 0; r < 4; ++r) {
                int gm = m0 + wm + i * 16 + lhi * 4 + r;
                int gn = n0 + wn + j * 16 + l15;
                Cf[(size_t)gm * N + gn] = acc[i][j][r];
            }
}

// ---------------------------------------------------------------------------
// Transpose V per head: Vh[head][s][d] -> Vt[head][d][s]
// ---------------------------------------------------------------------------
__global__ __launch_bounds__(256) void transpose_v(const bf16* __restrict__ Vh,
                                                   bf16* __restrict__ Vt) {
    __shared__ bf16 T[64 * 64];
    const int tid = threadIdx.x;
    const int s0 = blockIdx.x * 64, d0 = blockIdx.y * 64, head = blockIdx.z;
    const bf16* src = Vh + ((size_t)head * SS) * HD;
    bf16* dst = Vt + ((size_t)head * HD) * SS;

#pragma unroll
    for (int i = 0; i < 2; ++i) {
        int id = tid + i * 256;
        int r = id >> 3, c16 = id & 7;
        bf16x8 v = *reinterpret_cast<const bf16x8*>(&src[(size_t)(s0 + r) * HD + d0 + c16 * 8]);
        int sw = c16 ^ ((r ^ (r >> 3)) & 7);
        *reinterpret_cast<bf16x8*>((char*)T + r * 128 + sw * 16) = v;
    }
    __syncthreads();
#pragma unroll
    for (int i = 0; i < 2; ++i) {
        int id = tid + i * 256;
        int dr = id >> 3, sc8 = (id & 7) * 8;
        bf16x8 o;
#pragma unroll
        for (int j = 0; j < 8; ++j) {
            int r = sc8 + j;
            int sw = (dr >> 3) ^ ((r ^ (r >> 3)) & 7);
            o[j] = *reinterpret_cast<const bf16*>((char*)T + r * 128 + sw * 16 + (dr & 7) * 2);
        }
        *reinterpret_cast<bf16x8*>(&dst[(size_t)(d0 + dr) * SS + s0 + sc8]) = o;
    }
}

// ---------------------------------------------------------------------------
// RoPE (rotate_half), vectorized
// ---------------------------------------------------------------------------
__global__ __launch_bounds__(256) void rope_kernel(bf16* __restrict__ Qh, bf16* __restrict__ Kh,
                                                   const float* __restrict__ cosT,
                                                   const float* __restrict__ sinT) {
    int idx = blockIdx.x * 256 + threadIdx.x;
    int g = idx & 7;
    int s = (idx >> 3) & (SS - 1);
    int head = idx >> 14;
    int d0 = g * 8;
    size_t base = ((size_t)head * SS + s) * HD;
    f32x4 ca = *reinterpret_cast<const f32x4*>(&cosT[s * HD + d0]);
    f32x4 cb = *reinterpret_cast<const f32x4*>(&cosT[s * HD + d0 + 4]);
    f32x4 sa = *reinterpret_cast<const f32x4*>(&sinT[s * HD + d0]);
    f32x4 sb = *reinterpret_cast<const f32x4*>(&sinT[s * HD + d0 + 4]);
    bf16x8 ql = *reinterpret_cast<const bf16x8*>(&Qh[base + d0]);
    bf16x8 qh = *reinterpret_cast<const bf16x8*>(&Qh[base + 64 + d0]);
    bf16x8 kl = *reinterpret_cast<const bf16x8*>(&Kh[base + d0]);
    bf16x8 kh = *reinterpret_cast<const bf16x8*>(&Kh[base + 64 + d0]);
    bf16x8 qlo, qhi, klo, khi;
#pragma unroll
    for (int j = 0; j < 8; ++j) {
        float c = (j < 4) ? ca[j] : cb[j - 4];
        float sn = (j < 4) ? sa[j] : sb[j - 4];
        float q0 = (float)ql[j], q1 = (float)qh[j];
        float k0 = (float)kl[j], k1 = (float)kh[j];
        qlo[j] = (bf16)(q0 * c - q1 * sn);
        qhi[j] = (bf16)(q1 * c + q0 * sn);
        klo[j] = (bf16)(k0 * c - k1 * sn);
        khi[j] = (bf16)(k1 * c + k0 * sn);
    }
    *reinterpret_cast<bf16x8*>(&Qh[base + d0]) = qlo;
    *reinterpret_cast<bf16x8*>(&Qh[base + 64 + d0]) = qhi;
    *reinterpret_cast<bf16x8*>(&Kh[base + d0]) = klo;
    *reinterpret_cast<bf16x8*>(&Kh[base + 64 + d0]) = khi;
}

// ---------------------------------------------------------------------------
// Causal flash attention, 512 threads = 8 waves x 16 q-rows (QB=128), KV=64.
// K double-buffered LDS, V single-buffered (issue-early/write-late regs),
// XOR-swizzled, defer-max softmax. LDS 66 KiB -> 2 blocks/CU (16 waves/CU).
// Grid 512: bid<256 -> light tile T=p&7; bid>=256 -> heavy 15-T (round-robin
// dispatch co-locates the balanced pair on one CU).
// ---------------------------------------------------------------------------
__global__ __launch_bounds__(512, 4) void attn_kernel(const bf16* __restrict__ Q,
                                                      const bf16* __restrict__ K,
                                                      const bf16* __restrict__ Vt,
                                                      bf16* __restrict__ Ob) {
    __shared__ bf16 Ks[2][64 * 128];   // 32 KiB
    __shared__ bf16 Vs[128 * 64];      // 16 KiB (d-major)
    __shared__ bf16 Ps[8][16 * 72];    // 18 KiB

    const int tid = threadIdx.x, lane = tid & 63, wave = tid >> 6;
    const int l15 = lane & 15, lhi = lane >> 4;
    const int p = blockIdx.x & 255;
    const int head = p >> 3;
    const int Tl = p & 7;
    const int T = (blockIdx.x >> 8) ? (15 - Tl) : Tl;
    const int b = head >> 4, h = head & (NH - 1);
    const size_t hb = (size_t)head * SS * HD;
    const bf16* Vth = Vt + (size_t)head * HD * SS;
    const float cexp = 0.08838834764831845f * 1.4426950408889634f;
    const float THR = 62.0f;

    const int q0 = T * 128;
    const int qw = q0 + wave * 16;
    const int nkv = 2 * T + 2;

    // K-chunk coords (2 per thread): 64 rows x 16 col-groups
    const int ka0 = tid >> 4, kc0 = (tid & 15) * 8;
    const int ka1 = (tid + 512) >> 4, kc1 = ((tid + 512) & 15) * 8;
    // V-chunk coords: 128 rows x 8 col-groups
    const int va0 = tid >> 3, vc0 = (tid & 7) * 8;
    const int va1 = (tid + 512) >> 3, vc1 = ((tid + 512) & 7) * 8;
    // swizzled LDS byte offsets
    const int ksw0 = (ka0 * 256 + kc0 * 2) ^ ((ka0 & 7) << 4);
    const int ksw1 = (ka1 * 256 + kc1 * 2) ^ ((ka1 & 7) << 4);
    const int vsw0 = (va0 * 128 + vc0 * 2) ^ ((va0 & 7) << 4);
    const int vsw1 = (va1 * 128 + vc1 * 2) ^ ((va1 & 7) << 4);

    bf16x8 qf[4];
#pragma unroll
    for (int ks = 0; ks < 4; ++ks)
        qf[ks] = *reinterpret_cast<const bf16x8*>(
            &Q[hb + (size_t)(qw + l15) * HD + ks * 32 + 8 * lhi]);

    f32x4 oacc[8] = {};
    float Mr[4], Lp[4];
#pragma unroll
    for (int r = 0; r < 4; ++r) { Mr[r] = -INFINITY; Lp[r] = 0.f; }

    // prologue: K(0)->LDS, issue K(1), V(0)->regs
    bf16x8 kr0 = *reinterpret_cast<const bf16x8*>(&K[hb + (size_t)ka0 * HD + kc0]);
    bf16x8 kr1 = *reinterpret_cast<const bf16x8*>(&K[hb + (size_t)ka1 * HD + kc1]);
    bf16x8 vr0 = *reinterpret_cast<const bf16x8*>(&Vth[(size_t)va0 * SS + vc0]);
    bf16x8 vr1 = *reinterpret_cast<const bf16x8*>(&Vth[(size_t)va1 * SS + vc1]);
    *reinterpret_cast<bf16x8*>((char*)Ks[0] + ksw0) = kr0;
    *reinterpret_cast<bf16x8*>((char*)Ks[0] + ksw1) = kr1;
    kr0 = *reinterpret_cast<const bf16x8*>(&K[hb + (size_t)(64 + ka0) * HD + kc0]);
    kr1 = *reinterpret_cast<const bf16x8*>(&K[hb + (size_t)(64 + ka1) * HD + kc1]);
    __syncthreads();

#pragma unroll 1
    for (int it = 0; it < nkv; ++it) {
        const int cur = it & 1;

        // ---- S = Q K^T from Ks[cur] ----
        f32x4 sf[4] = {};
#pragma unroll
        for (int ks = 0; ks < 4; ++ks) {
#pragma unroll
            for (int ne = 0; ne < 4; ++ne) {
                int row = ne * 16 + l15;
                bf16x8 kf = *reinterpret_cast<const bf16x8*>(
                    (const char*)Ks[cur] + ((row * 256 + (ks * 4 + lhi) * 16) ^ ((row & 7) << 4)));
                sf[ne] = __builtin_amdgcn_mfma_f32_16x16x32_bf16(qf[ks], kf, sf[ne], 0, 0, 0);
            }
        }

        // causal mask on the two diagonal-spanning tiles
        if (it + 2 >= nkv) {
#pragma unroll
            for (int ne = 0; ne < 4; ++ne)
#pragma unroll
                for (int r = 0; r < 4; ++r) {
                    int gq = qw + lhi * 4 + r;
                    int gk = it * 64 + ne * 16 + l15;
                    if (gk > gq) sf[ne][r] = -INFINITY;
                }
        }

        // ---- defer-max online softmax ----
        float lm[4];
#pragma unroll
        for (int r = 0; r < 4; ++r)
            lm[r] = fmaxf(fmaxf(sf[0][r], sf[1][r]), fmaxf(sf[2][r], sf[3][r]));
        bool need = (lm[0] > Mr[0] + THR) || (lm[1] > Mr[1] + THR) ||
                    (lm[2] > Mr[2] + THR) || (lm[3] > Mr[3] + THR);
        if (__any(need)) {
            float rmax[4] = {lm[0], lm[1], lm[2], lm[3]};
#pragma unroll
            for (int m = 1; m < 16; m <<= 1)
#pragma unroll
                for (int r = 0; r < 4; ++r)
                    rmax[r] = fmaxf(rmax[r], __shfl_xor(rmax[r], m));
#pragma unroll
            for (int r = 0; r < 4; ++r) {
                float nM = fmaxf(Mr[r], rmax[r]);
                float scf = __builtin_amdgcn_exp2f((Mr[r] - nM) * cexp);
                Mr[r] = nM;
                Lp[r] *= scf;
#pragma unroll
                for (int nf = 0; nf < 8; ++nf) oacc[nf][r] *= scf;
            }
        }
#pragma unroll
        for (int ne = 0; ne < 4; ++ne)
#pragma unroll
            for (int r = 0; r < 4; ++r) {
                float pv = __builtin_amdgcn_exp2f((sf[ne][r] - Mr[r]) * cexp);
                Lp[r] += pv;
                Ps[wave][(lhi * 4 + r) * 72 + ne * 16 + l15] = (bf16)pv;
            }

        // ---- B1: all waves done with PV(it-1) reads of Vs / old Ks reads ----
        __syncthreads();

        // write V(it) -> Vs; write K(it+1) -> Ks[cur^1]; issue next loads
        *reinterpret_cast<bf16x8*>((char*)Vs + vsw0) = vr0;
        *reinterpret_cast<bf16x8*>((char*)Vs + vsw1) = vr1;
        if (it + 1 < nkv) {
            *reinterpret_cast<bf16x8*>((char*)Ks[cur ^ 1] + ksw0) = kr0;
            *reinterpret_cast<bf16x8*>((char*)Ks[cur ^ 1] + ksw1) = kr1;
            const int kv1 = (it + 1) * 64;
            vr0 = *reinterpret_cast<const bf16x8*>(&Vth[(size_t)va0 * SS + kv1 + vc0]);
            vr1 = *reinterpret_cast<const bf16x8*>(&Vth[(size_t)va1 * SS + kv1 + vc1]);
        }
        if (it + 2 < nkv) {
            const int kv2 = (it + 2) * 64;
            kr0 = *reinterpret_cast<const bf16x8*>(&K[hb + (size_t)(kv2 + ka0) * HD + kc0]);
            kr1 = *reinterpret_cast<const bf16x8*>(&K[hb + (size_t)(kv2 + ka1) * HD + kc1]);
        }

        // ---- B2: Vs/Ks writes visible ----
        __syncthreads();

        // ---- O += P @ V ----
#pragma unroll
        for (int ks = 0; ks < 2; ++ks) {
            bf16x8 pa = *reinterpret_cast<const bf16x8*>(
                &Ps[wave][l15 * 72 + ks * 32 + 8 * lhi]);
#pragma unroll
            for (int nf = 0; nf < 8; ++nf) {
                int row = nf * 16 + l15;
                bf16x8 vb = *reinterpret_cast<const bf16x8*>(
                    (const char*)Vs + ((row * 128 + (ks * 4 + lhi) * 16) ^ ((row & 7) << 4)));
                oacc[nf] = __builtin_amdgcn_mfma_f32_16x16x32_bf16(pa, vb, oacc[nf], 0, 0, 0);
            }
        }
    }

    // ---- final L reduce + epilogue: write [B*S][H] bf16 ----
#pragma unroll
    for (int m = 1; m < 16; m <<= 1)
#pragma unroll
        for (int r = 0; r < 4; ++r)
            Lp[r] += __shfl_xor(Lp[r], m);
    float inv[4];
#pragma unroll
    for (int r = 0; r < 4; ++r) inv[r] = 1.f / Lp[r];
#pragma unroll
    for (int nf = 0; nf < 8; ++nf)
#pragma unroll
        for (int r = 0; r < 4; ++r) {
            int s = qw + lhi * 4 + r;
            int d = nf * 16 + l15;
            Ob[((size_t)(b * SS + s)) * HH + h * HD + d] = (bf16)(oacc[nf][r] * inv[r]);
        }
}

// ---------------------------------------------------------------------------
extern "C" void kernel_launch(void* const* d_in, const int* in_sizes, int n_in,
                              void* d_out, int out_size, void* d_ws, size_t ws_size,
                              hipStream_t stream) {
    const float* hs   = (const float*)d_in[0];
    const float* cosT = (const float*)d_in[2];
    const float* sinT = (const float*)d_in[3];
    const float* Wq   = (const float*)d_in[4];
    const float* Wk   = (const float*)d_in[5];
    const float* Wv   = (const float*)d_in[6];
    const float* Wo   = (const float*)d_in[7];
    float* out = (float*)d_out;

    char* w = (char*)d_ws;
    auto alloc = [&](size_t bytes) {
        char* p = w;
        w += (bytes + 255) & ~(size_t)255;
        return p;
    };
    const size_t XE = (size_t)BB * SS * HH;
    const size_t WE = (size_t)HH * HH;
    bf16* Xb   = (bf16*)alloc(XE * 2);
    bf16* Wqkv = (bf16*)alloc(3 * WE * 2);
    bf16* Wob  = (bf16*)alloc(WE * 2);
    bf16* QKV  = (bf16*)alloc(3 * XE * 2);
    bf16* Vtg  = (bf16*)alloc(XE * 2);
    bf16* Ob   = (bf16*)alloc(XE * 2);

    const int M = BB * SS;  // 4096
    bf16* Qh = QKV;
    bf16* Kh = QKV + XE;
    bf16* Vh = QKV + 2 * XE;

    {
        int total4 = (int)((XE + 4 * WE) / 4);
        cast_all<<<(total4 + 255) / 256, 256, 0, stream>>>(hs, Wq, Wk, Wv, Wo, Xb, Wqkv, Wob);
    }

    // fused QKV projection: M=4096, N=6144, K=2048, 256^2 8-phase
    gemm256_qkv<<<dim3((M / 256) * (3 * HH / 256)), 512, 0, stream>>>(Xb, Wqkv, QKV, M, 3 * HH, HH);

    rope_kernel<<<(BB * NH * SS * 8) / 256, 256, 0, stream>>>(Qh, Kh, cosT, sinT);

    dim3 tgrid(SS / 64, HD / 64, BB * NH);
    transpose_v<<<tgrid, 256, 0, stream>>>(Vh, Vtg);

    attn_kernel<<<512, 512, 0, stream>>>(Qh, Kh, Vtg, Ob);

    dim3 ogrid(HH / 128, M / 128);
    gemm_bt<<<ogrid, 256, 0, stream>>>(Ob, Wob, out, M, HH, HH);
}

// Round 8
// 308.290 us; speedup vs baseline: 1.1268x; 1.1268x over previous
//
#include <hip/hip_runtime.h>
#include <hip/hip_bf16.h>

typedef __bf16 bf16;
typedef __attribute__((ext_vector_type(8))) __bf16 bf16x8;
typedef __attribute__((ext_vector_type(4))) __bf16 bf16x4;
typedef __attribute__((ext_vector_type(4))) float f32x4;

// Problem constants
#define BB 2
#define SS 2048
#define HH 2048
#define NH 16
#define HD 128

#define GLOAD_LDS16(g, l)                                                  \
    __builtin_amdgcn_global_load_lds(                                      \
        (const __attribute__((address_space(1))) void*)(g),                \
        (__attribute__((address_space(3))) void*)(l), 16, 0, 0)

// ---------------------------------------------------------------------------
// Batched fp32 -> bf16 cast: X then Wq,Wk,Wv (into contiguous Wqkv), Wo.
// ---------------------------------------------------------------------------
__global__ __launch_bounds__(256) void cast_all(const float* __restrict__ hs,
                                                const float* __restrict__ Wq,
                                                const float* __restrict__ Wk,
                                                const float* __restrict__ Wv,
                                                const float* __restrict__ Wo,
                                                bf16* __restrict__ Xb,
                                                bf16* __restrict__ Wqkv,
                                                bf16* __restrict__ Wob) {
    const int XE4 = (BB * SS * HH) / 4;
    const int WE4 = (HH * HH) / 4;
    int i = blockIdx.x * 256 + threadIdx.x;
    const float* src;
    bf16* dst;
    int off;
    if (i < XE4) { src = hs; dst = Xb; off = i; }
    else if (i < XE4 + WE4) { src = Wq; dst = Wqkv; off = i - XE4; }
    else if (i < XE4 + 2 * WE4) { src = Wk; dst = Wqkv + (size_t)HH * HH; off = i - XE4 - WE4; }
    else if (i < XE4 + 3 * WE4) { src = Wv; dst = Wqkv + 2 * (size_t)HH * HH; off = i - XE4 - 2 * WE4; }
    else { src = Wo; dst = Wob; off = i - XE4 - 3 * WE4; }
    f32x4 v = *reinterpret_cast<const f32x4*>(src + (size_t)off * 4);
    bf16x4 o;
    o[0] = (bf16)v[0]; o[1] = (bf16)v[1]; o[2] = (bf16)v[2]; o[3] = (bf16)v[3];
    *reinterpret_cast<bf16x4*>(dst + (size_t)off * 4) = o;
}

// ---------------------------------------------------------------------------
// 256x256-tile 8-phase GEMM, QKV epilogue. n-major XCD chunking:
// each XCD owns 3 n-columns x 16 m-rows -> B working set 3MB (L2-resident).
// ---------------------------------------------------------------------------
__global__ __launch_bounds__(512, 2) void gemm256_qkv(const bf16* __restrict__ A,
                                                      const bf16* __restrict__ B,
                                                      bf16* __restrict__ Cb,
                                                      int M, int N, int K) {
    __shared__ bf16 LA[2][256 * 64];
    __shared__ bf16 LB[2][256 * 64];
    const int tid = threadIdx.x, lane = tid & 63, wave = tid >> 6;
    const int l15 = lane & 15, lhi = lane >> 4;
    const int wr = wave >> 2, wc = wave & 3;
    const int NBY = M >> 8;                                // 16 m-tiles
    const int cpx = gridDim.x >> 3;                        // nwg % 8 == 0
    const int wg = (blockIdx.x & 7) * cpx + (blockIdx.x >> 3);
    const int m0 = (wg % NBY) * 256, n0 = (wg / NBY) * 256;   // n-major chunks
    const int NK = K >> 6;
    const int xorR = (l15 & 7) << 4;

    auto stageA = [&](int buf, int t, int h) {
        const int k0 = t << 6;
#pragma unroll
        for (int j = 0; j < 2; ++j) {
            int Xw = ((j * 128 + h * 64) << 7) + (wave << 10);
            int X = Xw + lane * 16;
            int T = X ^ (((X >> 7) & 7) << 4);
            GLOAD_LDS16(&A[(size_t)(m0 + (T >> 7)) * K + k0 + ((T & 127) >> 1)],
                        (char*)LA[buf] + Xw);
        }
    };
    auto stageB = [&](int buf, int t, int h) {
        const int k0 = t << 6;
#pragma unroll
        for (int j = 0; j < 2; ++j) {
            int base_row = h * 32 + (2 * j + (wave >> 2)) * 64;
            int Xw = (base_row << 7) + ((wave & 3) << 10);
            int X = Xw + lane * 16;
            int T = X ^ (((X >> 7) & 7) << 4);
            GLOAD_LDS16(&B[(size_t)(n0 + (T >> 7)) * K + k0 + ((T & 127) >> 1)],
                        (char*)LB[buf] + Xw);
        }
    };

    f32x4 acc[8][4] = {};

    stageA(0, 0, 0); stageB(0, 0, 0); stageB(0, 0, 1); stageA(0, 0, 1);
    stageA(1, 1, 0); stageB(1, 1, 1);
    asm volatile("s_waitcnt vmcnt(4)" ::: "memory");
    __builtin_amdgcn_s_barrier();

    bf16x8 af[4][2], bv0[2][2], bv1[2][2];

#pragma unroll 1
    for (int t = 0; t < NK; ++t) {
        const int buf = t & 1;
        char* lA = (char*)LA[buf];
        char* lB = (char*)LB[buf];

        // q0: (0,0); read A0(8)+B0(4); stage B0(t+1)
#pragma unroll
        for (int f = 0; f < 4; ++f)
#pragma unroll
            for (int ks = 0; ks < 2; ++ks) {
                int T = ((wr * 128 + f * 16 + l15) << 7) + ks * 64 + lhi * 16;
                af[f][ks] = *reinterpret_cast<const bf16x8*>(lA + (T ^ xorR));
            }
#pragma unroll
        for (int g = 0; g < 2; ++g)
#pragma unroll
            for (int ks = 0; ks < 2; ++ks) {
                int T = ((wc * 64 + g * 16 + l15) << 7) + ks * 64 + lhi * 16;
                bv0[g][ks] = *reinterpret_cast<const bf16x8*>(lB + (T ^ xorR));
            }
        if (t + 1 < NK) stageB(buf ^ 1, t + 1, 0);
        __builtin_amdgcn_s_barrier();
        asm volatile("s_waitcnt lgkmcnt(0)" ::: "memory");
        __builtin_amdgcn_s_setprio(1);
#pragma unroll
        for (int f = 0; f < 4; ++f)
#pragma unroll
            for (int g = 0; g < 2; ++g)
#pragma unroll
                for (int ks = 0; ks < 2; ++ks)
                    acc[f][g] = __builtin_amdgcn_mfma_f32_16x16x32_bf16(af[f][ks], bv0[g][ks], acc[f][g], 0, 0, 0);
        __builtin_amdgcn_s_setprio(0);
        __builtin_amdgcn_s_barrier();

        // q1: (0,1); read B1(4); stage A1(t+1)
#pragma unroll
        for (int g = 0; g < 2; ++g)
#pragma unroll
            for (int ks = 0; ks < 2; ++ks) {
                int T = ((wc * 64 + 32 + g * 16 + l15) << 7) + ks * 64 + lhi * 16;
                bv1[g][ks] = *reinterpret_cast<const bf16x8*>(lB + (T ^ xorR));
            }
        if (t + 1 < NK) stageA(buf ^ 1, t + 1, 1);
        __builtin_amdgcn_s_barrier();
        asm volatile("s_waitcnt lgkmcnt(0)" ::: "memory");
        __builtin_amdgcn_s_setprio(1);
#pragma unroll
        for (int f = 0; f < 4; ++f)
#pragma unroll
            for (int g = 0; g < 2; ++g)
#pragma unroll
                for (int ks = 0; ks < 2; ++ks)
                    acc[f][2 + g] = __builtin_amdgcn_mfma_f32_16x16x32_bf16(af[f][ks], bv1[g][ks], acc[f][2 + g], 0, 0, 0);
        __builtin_amdgcn_s_setprio(0);
        __builtin_amdgcn_s_barrier();

        // q2: (1,1); read A1(8); stage A0(t+2)
#pragma unroll
        for (int f = 0; f < 4; ++f)
#pragma unroll
            for (int ks = 0; ks < 2; ++ks) {
                int T = ((wr * 128 + 64 + f * 16 + l15) << 7) + ks * 64 + lhi * 16;
                af[f][ks] = *reinterpret_cast<const bf16x8*>(lA + (T ^ xorR));
            }
        if (t + 2 < NK) stageA(buf, t + 2, 0);
        __builtin_amdgcn_s_barrier();
        asm volatile("s_waitcnt lgkmcnt(0)" ::: "memory");
        __builtin_amdgcn_s_setprio(1);
#pragma unroll
        for (int f = 0; f < 4; ++f)
#pragma unroll
            for (int g = 0; g < 2; ++g)
#pragma unroll
                for (int ks = 0; ks < 2; ++ks)
                    acc[4 + f][2 + g] = __builtin_amdgcn_mfma_f32_16x16x32_bf16(af[f][ks], bv1[g][ks], acc[4 + f][2 + g], 0, 0, 0);
        __builtin_amdgcn_s_setprio(0);
        __builtin_amdgcn_s_barrier();

        // q3: (1,0); no reads; stage B1(t+2)
        if (t + 2 < NK) stageB(buf, t + 2, 1);
        __builtin_amdgcn_s_barrier();
        __builtin_amdgcn_s_setprio(1);
#pragma unroll
        for (int f = 0; f < 4; ++f)
#pragma unroll
            for (int g = 0; g < 2; ++g)
#pragma unroll
                for (int ks = 0; ks < 2; ++ks)
                    acc[4 + f][g] = __builtin_amdgcn_mfma_f32_16x16x32_bf16(af[f][ks], bv0[g][ks], acc[4 + f][g], 0, 0, 0);
        __builtin_amdgcn_s_setprio(0);
        if (t + 2 == NK) {
            asm volatile("s_waitcnt vmcnt(0)" ::: "memory");
        } else if (t + 1 < NK) {
            asm volatile("s_waitcnt vmcnt(4)" ::: "memory");
        }
        __builtin_amdgcn_s_barrier();
    }

#pragma unroll
    for (int mf = 0; mf < 8; ++mf)
#pragma unroll
        for (int nf = 0; nf < 4; ++nf)
#pragma unroll
            for (int r = 0; r < 4; ++r) {
                int gm = m0 + wr * 128 + mf * 16 + lhi * 4 + r;
                int gn = n0 + wc * 64 + nf * 16 + l15;
                int proj = gn >> 11, n2 = gn & 2047;
                int b = gm >> 11, s = gm & (SS - 1);
                int h = n2 >> 7, d = n2 & (HD - 1);
                Cb[((size_t)proj << 23) + ((((size_t)(b * NH + h)) * SS + s) << 7) + d] =
                    (bf16)acc[mf][nf][r];
            }
}

// ---------------------------------------------------------------------------
// 128x128 GEMM (m97 structure), fp32 epilogue (out projection). 1D grid,
// n-major XCD chunking: each XCD owns 2 n-cols x 32 m -> B/XCD = 1MB (L2).
// ---------------------------------------------------------------------------
__global__ __launch_bounds__(256) void gemm_bt(const bf16* __restrict__ A,
                                               const bf16* __restrict__ B,
                                               float* __restrict__ Cf,
                                               int M, int N, int K) {
    __shared__ bf16 As[128 * 64];
    __shared__ bf16 Bs[128 * 64];
    const int tid = threadIdx.x;
    const int lane = tid & 63, wave = tid >> 6;
    const int l15 = lane & 15, lhi = lane >> 4;
    const int NBY = M >> 7;                                // 32 m-tiles
    const int cpx = gridDim.x >> 3;
    const int wg = (blockIdx.x & 7) * cpx + (blockIdx.x >> 3);
    const int m0 = (wg % NBY) * 128, n0 = (wg / NBY) * 128;
    const int wm = (wave >> 1) * 64, wn = (wave & 1) * 64;
    const int lrow = lane >> 3;
    const int lcol = (lane & 7) * 8;

    f32x4 acc[4][4] = {};

    for (int k0 = 0; k0 < K; k0 += 64) {
#pragma unroll
        for (int j = 0; j < 4; ++j) {
            const int c = wave * 4 + j;
            const int row = c * 8 + lrow;
            GLOAD_LDS16(&A[(size_t)(m0 + row) * K + k0 + lcol], &As[c * 512]);
            GLOAD_LDS16(&B[(size_t)(n0 + row) * K + k0 + lcol], &Bs[c * 512]);
        }
        __syncthreads();
#pragma unroll
        for (int ks = 0; ks < 2; ++ks) {
            bf16x8 af[4], bfr[4];
#pragma unroll
            for (int i = 0; i < 4; ++i)
                af[i] = *reinterpret_cast<const bf16x8*>(&As[(wm + i * 16 + l15) * 64 + ks * 32 + 8 * lhi]);
#pragma unroll
            for (int j = 0; j < 4; ++j)
                bfr[j] = *reinterpret_cast<const bf16x8*>(&Bs[(wn + j * 16 + l15) * 64 + ks * 32 + 8 * lhi]);
#pragma unroll
            for (int i = 0; i < 4; ++i)
#pragma unroll
                for (int j = 0; j < 4; ++j)
                    acc[i][j] = __builtin_amdgcn_mfma_f32_16x16x32_bf16(af[i], bfr[j], acc[i][j], 0, 0, 0);
        }
        __syncthreads();
    }

#pragma unroll
    for (int i = 0; i < 4; ++i)
#pragma unroll
        for (int j = 0; j < 4; ++j)
#pragma unroll
            for (int r = 0; r < 4; ++r) {
                int gm = m0 + wm + i * 16 + lhi * 4 + r;
                int gn = n0 + wn + j * 16 + l15;
                Cf[(size_t)gm * N + gn] = acc[i][j][r];
            }
}

// ---------------------------------------------------------------------------
// Transpose V per head: Vh[head][s][d] -> Vt[head][d][s]
// ---------------------------------------------------------------------------
__global__ __launch_bounds__(256) void transpose_v(const bf16* __restrict__ Vh,
                                                   bf16* __restrict__ Vt) {
    __shared__ bf16 T[64 * 64];
    const int tid = threadIdx.x;
    const int s0 = blockIdx.x * 64, d0 = blockIdx.y * 64, head = blockIdx.z;
    const bf16* src = Vh + ((size_t)head * SS) * HD;
    bf16* dst = Vt + ((size_t)head * HD) * SS;

#pragma unroll
    for (int i = 0; i < 2; ++i) {
        int id = tid + i * 256;
        int r = id >> 3, c16 = id & 7;
        bf16x8 v = *reinterpret_cast<const bf16x8*>(&src[(size_t)(s0 + r) * HD + d0 + c16 * 8]);
        int sw = c16 ^ ((r ^ (r >> 3)) & 7);
        *reinterpret_cast<bf16x8*>((char*)T + r * 128 + sw * 16) = v;
    }
    __syncthreads();
#pragma unroll
    for (int i = 0; i < 2; ++i) {
        int id = tid + i * 256;
        int dr = id >> 3, sc8 = (id & 7) * 8;
        bf16x8 o;
#pragma unroll
        for (int j = 0; j < 8; ++j) {
            int r = sc8 + j;
            int sw = (dr >> 3) ^ ((r ^ (r >> 3)) & 7);
            o[j] = *reinterpret_cast<const bf16*>((char*)T + r * 128 + sw * 16 + (dr & 7) * 2);
        }
        *reinterpret_cast<bf16x8*>(&dst[(size_t)(d0 + dr) * SS + s0 + sc8]) = o;
    }
}

// ---------------------------------------------------------------------------
// RoPE (rotate_half), vectorized
// ---------------------------------------------------------------------------
__global__ __launch_bounds__(256) void rope_kernel(bf16* __restrict__ Qh, bf16* __restrict__ Kh,
                                                   const float* __restrict__ cosT,
                                                   const float* __restrict__ sinT) {
    int idx = blockIdx.x * 256 + threadIdx.x;
    int g = idx & 7;
    int s = (idx >> 3) & (SS - 1);
    int head = idx >> 14;
    int d0 = g * 8;
    size_t base = ((size_t)head * SS + s) * HD;
    f32x4 ca = *reinterpret_cast<const f32x4*>(&cosT[s * HD + d0]);
    f32x4 cb = *reinterpret_cast<const f32x4*>(&cosT[s * HD + d0 + 4]);
    f32x4 sa = *reinterpret_cast<const f32x4*>(&sinT[s * HD + d0]);
    f32x4 sb = *reinterpret_cast<const f32x4*>(&sinT[s * HD + d0 + 4]);
    bf16x8 ql = *reinterpret_cast<const bf16x8*>(&Qh[base + d0]);
    bf16x8 qh = *reinterpret_cast<const bf16x8*>(&Qh[base + 64 + d0]);
    bf16x8 kl = *reinterpret_cast<const bf16x8*>(&Kh[base + d0]);
    bf16x8 kh = *reinterpret_cast<const bf16x8*>(&Kh[base + 64 + d0]);
    bf16x8 qlo, qhi, klo, khi;
#pragma unroll
    for (int j = 0; j < 8; ++j) {
        float c = (j < 4) ? ca[j] : cb[j - 4];
        float sn = (j < 4) ? sa[j] : sb[j - 4];
        float q0 = (float)ql[j], q1 = (float)qh[j];
        float k0 = (float)kl[j], k1 = (float)kh[j];
        qlo[j] = (bf16)(q0 * c - q1 * sn);
        qhi[j] = (bf16)(q1 * c + q0 * sn);
        klo[j] = (bf16)(k0 * c - k1 * sn);
        khi[j] = (bf16)(k1 * c + k0 * sn);
    }
    *reinterpret_cast<bf16x8*>(&Qh[base + d0]) = qlo;
    *reinterpret_cast<bf16x8*>(&Qh[base + 64 + d0]) = qhi;
    *reinterpret_cast<bf16x8*>(&Kh[base + d0]) = klo;
    *reinterpret_cast<bf16x8*>(&Kh[base + 64 + d0]) = khi;
}

// ---------------------------------------------------------------------------
// Causal flash attention (R5 proven version): load-balanced pairs, K/V
// double-buffered, XOR-swizzled, defer-max. grid 512, block 256 (4 waves).
// ---------------------------------------------------------------------------
__global__ __launch_bounds__(256) void attn_kernel(const bf16* __restrict__ Q,
                                                   const bf16* __restrict__ K,
                                                   const bf16* __restrict__ Vt,
                                                   bf16* __restrict__ Ob) {
    __shared__ bf16 Ks[2][64 * 128];
    __shared__ bf16 Vs[2][128 * 64];
    __shared__ bf16 Ps[4][16][72];

    const int tid = threadIdx.x, lane = tid & 63, wave = tid >> 6;
    const int l15 = lane & 15, lhi = lane >> 4;
    const int bid = blockIdx.x;
    const int orig = (bid & 7) * 64 + (bid >> 3);   // XCD swizzle
    const int head = orig >> 4;
    const int pi = orig & 15;
    const int b = head >> 4, h = head & (NH - 1);
    const size_t hb = (size_t)head * SS * HD;
    const bf16* Vth = Vt + (size_t)head * HD * SS;
    const float cexp = 0.08838834764831845f * 1.4426950408889634f;
    const float THR = 62.0f;

#pragma unroll 1
    for (int part = 0; part < 2; ++part) {
        const int t = part ? (31 - pi) : pi;
        const int q0 = t * 64;
        const int qw = q0 + wave * 16;
        const int nkv = t + 1;

        bf16x8 qf[4];
#pragma unroll
        for (int ks = 0; ks < 4; ++ks)
            qf[ks] = *reinterpret_cast<const bf16x8*>(
                &Q[hb + (size_t)(qw + l15) * HD + ks * 32 + 8 * lhi]);

        f32x4 oacc[8] = {};
        float Mr[4], Lp[4];
#pragma unroll
        for (int r = 0; r < 4; ++r) { Mr[r] = -INFINITY; Lp[r] = 0.f; }

        bf16x8 kr[4], vr[4];
#pragma unroll
        for (int i = 0; i < 4; ++i) {
            int id = tid + i * 256;
            kr[i] = *reinterpret_cast<const bf16x8*>(&K[hb + (size_t)(id >> 4) * HD + (id & 15) * 8]);
            vr[i] = *reinterpret_cast<const bf16x8*>(&Vth[(size_t)(id >> 3) * SS + (id & 7) * 8]);
        }
#pragma unroll
        for (int i = 0; i < 4; ++i) {
            int id = tid + i * 256;
            int krow = id >> 4, kc = id & 15;
            *reinterpret_cast<bf16x8*>((char*)Ks[0] + ((krow * 256 + kc * 16) ^ ((krow & 7) << 4))) = kr[i];
            int vrow = id >> 3, vc = id & 7;
            *reinterpret_cast<bf16x8*>((char*)Vs[0] + ((vrow * 128 + vc * 16) ^ ((vrow & 7) << 4))) = vr[i];
        }
        __syncthreads();

        for (int it = 0; it < nkv; ++it) {
            const int cur = it & 1;
            const bool pre = (it + 1 < nkv);
            if (pre) {
                const int kv0 = (it + 1) * 64;
#pragma unroll
                for (int i = 0; i < 4; ++i) {
                    int id = tid + i * 256;
                    kr[i] = *reinterpret_cast<const bf16x8*>(&K[hb + (size_t)(kv0 + (id >> 4)) * HD + (id & 15) * 8]);
                    vr[i] = *reinterpret_cast<const bf16x8*>(&Vth[(size_t)(id >> 3) * SS + kv0 + (id & 7) * 8]);
                }
            }

            f32x4 sf[4] = {};
#pragma unroll
            for (int ks = 0; ks < 4; ++ks) {
#pragma unroll
                for (int ne = 0; ne < 4; ++ne) {
                    int row = ne * 16 + l15;
                    bf16x8 kf = *reinterpret_cast<const bf16x8*>(
                        (const char*)Ks[cur] + ((row * 256 + (ks * 4 + lhi) * 16) ^ ((row & 7) << 4)));
                    sf[ne] = __builtin_amdgcn_mfma_f32_16x16x32_bf16(qf[ks], kf, sf[ne], 0, 0, 0);
                }
            }

            if (it == nkv - 1) {
#pragma unroll
                for (int ne = 0; ne < 4; ++ne)
#pragma unroll
                    for (int r = 0; r < 4; ++r) {
                        int gq = qw + lhi * 4 + r;
                        int gk = it * 64 + ne * 16 + l15;
                        if (gk > gq) sf[ne][r] = -INFINITY;
                    }
            }

            float lm[4];
#pragma unroll
            for (int r = 0; r < 4; ++r)
                lm[r] = fmaxf(fmaxf(sf[0][r], sf[1][r]), fmaxf(sf[2][r], sf[3][r]));
            bool need = (lm[0] > Mr[0] + THR) || (lm[1] > Mr[1] + THR) ||
                        (lm[2] > Mr[2] + THR) || (lm[3] > Mr[3] + THR);
            if (__any(need)) {
                float rmax[4] = {lm[0], lm[1], lm[2], lm[3]};
#pragma unroll
                for (int m = 1; m < 16; m <<= 1)
#pragma unroll
                    for (int r = 0; r < 4; ++r)
                        rmax[r] = fmaxf(rmax[r], __shfl_xor(rmax[r], m));
#pragma unroll
                for (int r = 0; r < 4; ++r) {
                    float nM = fmaxf(Mr[r], rmax[r]);
                    float scf = __builtin_amdgcn_exp2f((Mr[r] - nM) * cexp);
                    Mr[r] = nM;
                    Lp[r] *= scf;
#pragma unroll
                    for (int nf = 0; nf < 8; ++nf) oacc[nf][r] *= scf;
                }
            }
#pragma unroll
            for (int ne = 0; ne < 4; ++ne)
#pragma unroll
                for (int r = 0; r < 4; ++r) {
                    float p = __builtin_amdgcn_exp2f((sf[ne][r] - Mr[r]) * cexp);
                    Lp[r] += p;
                    Ps[wave][lhi * 4 + r][ne * 16 + l15] = (bf16)p;
                }

#pragma unroll
            for (int ks = 0; ks < 2; ++ks) {
                bf16x8 pa = *reinterpret_cast<const bf16x8*>(&Ps[wave][l15][ks * 32 + 8 * lhi]);
#pragma unroll
                for (int nf = 0; nf < 8; ++nf) {
                    int row = nf * 16 + l15;
                    bf16x8 vb = *reinterpret_cast<const bf16x8*>(
                        (const char*)Vs[cur] + ((row * 128 + (ks * 4 + lhi) * 16) ^ ((row & 7) << 4)));
                    oacc[nf] = __builtin_amdgcn_mfma_f32_16x16x32_bf16(pa, vb, oacc[nf], 0, 0, 0);
                }
            }

            if (pre) {
#pragma unroll
                for (int i = 0; i < 4; ++i) {
                    int id = tid + i * 256;
                    int krow = id >> 4, kc = id & 15;
                    *reinterpret_cast<bf16x8*>((char*)Ks[cur ^ 1] + ((krow * 256 + kc * 16) ^ ((krow & 7) << 4))) = kr[i];
                    int vrow = id >> 3, vc = id & 7;
                    *reinterpret_cast<bf16x8*>((char*)Vs[cur ^ 1] + ((vrow * 128 + vc * 16) ^ ((vrow & 7) << 4))) = vr[i];
                }
            }
            __syncthreads();
        }

#pragma unroll
        for (int m = 1; m < 16; m <<= 1)
#pragma unroll
            for (int r = 0; r < 4; ++r)
                Lp[r] += __shfl_xor(Lp[r], m);
        float inv[4];
#pragma unroll
        for (int r = 0; r < 4; ++r) inv[r] = 1.f / Lp[r];
#pragma unroll
        for (int nf = 0; nf < 8; ++nf)
#pragma unroll
            for (int r = 0; r < 4; ++r) {
                int s = qw + lhi * 4 + r;
                int d = nf * 16 + l15;
                Ob[((size_t)(b * SS + s)) * HH + h * HD + d] = (bf16)(oacc[nf][r] * inv[r]);
            }
    }
}

// ---------------------------------------------------------------------------
extern "C" void kernel_launch(void* const* d_in, const int* in_sizes, int n_in,
                              void* d_out, int out_size, void* d_ws, size_t ws_size,
                              hipStream_t stream) {
    const float* hs   = (const float*)d_in[0];
    const float* cosT = (const float*)d_in[2];
    const float* sinT = (const float*)d_in[3];
    const float* Wq   = (const float*)d_in[4];
    const float* Wk   = (const float*)d_in[5];
    const float* Wv   = (const float*)d_in[6];
    const float* Wo   = (const float*)d_in[7];
    float* out = (float*)d_out;

    char* w = (char*)d_ws;
    auto alloc = [&](size_t bytes) {
        char* p = w;
        w += (bytes + 255) & ~(size_t)255;
        return p;
    };
    const size_t XE = (size_t)BB * SS * HH;
    const size_t WE = (size_t)HH * HH;
    bf16* Xb   = (bf16*)alloc(XE * 2);
    bf16* Wqkv = (bf16*)alloc(3 * WE * 2);
    bf16* Wob  = (bf16*)alloc(WE * 2);
    bf16* QKV  = (bf16*)alloc(3 * XE * 2);
    bf16* Vtg  = (bf16*)alloc(XE * 2);
    bf16* Ob   = (bf16*)alloc(XE * 2);

    const int M = BB * SS;  // 4096
    bf16* Qh = QKV;
    bf16* Kh = QKV + XE;
    bf16* Vh = QKV + 2 * XE;

    {
        int total4 = (int)((XE + 4 * WE) / 4);
        cast_all<<<(total4 + 255) / 256, 256, 0, stream>>>(hs, Wq, Wk, Wv, Wo, Xb, Wqkv, Wob);
    }

    // fused QKV projection: M=4096, N=6144, K=2048, 256^2 8-phase, n-major XCD
    gemm256_qkv<<<dim3((M / 256) * (3 * HH / 256)), 512, 0, stream>>>(Xb, Wqkv, QKV, M, 3 * HH, HH);

    rope_kernel<<<(BB * NH * SS * 8) / 256, 256, 0, stream>>>(Qh, Kh, cosT, sinT);

    dim3 tgrid(SS / 64, HD / 64, BB * NH);
    transpose_v<<<tgrid, 256, 0, stream>>>(Vh, Vtg);

    attn_kernel<<<512, 256, 0, stream>>>(Qh, Kh, Vtg, Ob);

    // out projection: M=4096, N=2048, K=2048, 1D grid, n-major XCD chunks
    gemm_bt<<<(M / 128) * (HH / 128), 256, 0, stream>>>(Ob, Wob, out, M, HH, HH);
}

// Round 9
// 298.413 us; speedup vs baseline: 1.1640x; 1.0331x over previous
//
#include <hip/hip_runtime.h>
#include <hip/hip_bf16.h>

typedef __bf16 bf16;
typedef __attribute__((ext_vector_type(8))) __bf16 bf16x8;
typedef __attribute__((ext_vector_type(4))) __bf16 bf16x4;
typedef __attribute__((ext_vector_type(4))) float f32x4;

// Problem constants
#define BB 2
#define SS 2048
#define HH 2048
#define NH 16
#define HD 128

#define GLOAD_LDS16(g, l)                                                  \
    __builtin_amdgcn_global_load_lds(                                      \
        (const __attribute__((address_space(1))) void*)(g),                \
        (__attribute__((address_space(3))) void*)(l), 16, 0, 0)

// ---------------------------------------------------------------------------
// Batched fp32 -> bf16 cast: X then Wq,Wk,Wv (into contiguous Wqkv), Wo.
// ---------------------------------------------------------------------------
__global__ __launch_bounds__(256) void cast_all(const float* __restrict__ hs,
                                                const float* __restrict__ Wq,
                                                const float* __restrict__ Wk,
                                                const float* __restrict__ Wv,
                                                const float* __restrict__ Wo,
                                                bf16* __restrict__ Xb,
                                                bf16* __restrict__ Wqkv,
                                                bf16* __restrict__ Wob) {
    const int XE4 = (BB * SS * HH) / 4;
    const int WE4 = (HH * HH) / 4;
    int i = blockIdx.x * 256 + threadIdx.x;
    const float* src;
    bf16* dst;
    int off;
    if (i < XE4) { src = hs; dst = Xb; off = i; }
    else if (i < XE4 + WE4) { src = Wq; dst = Wqkv; off = i - XE4; }
    else if (i < XE4 + 2 * WE4) { src = Wk; dst = Wqkv + (size_t)HH * HH; off = i - XE4 - WE4; }
    else if (i < XE4 + 3 * WE4) { src = Wv; dst = Wqkv + 2 * (size_t)HH * HH; off = i - XE4 - 2 * WE4; }
    else { src = Wo; dst = Wob; off = i - XE4 - 3 * WE4; }
    f32x4 v = *reinterpret_cast<const f32x4*>(src + (size_t)off * 4);
    bf16x4 o;
    o[0] = (bf16)v[0]; o[1] = (bf16)v[1]; o[2] = (bf16)v[2]; o[3] = (bf16)v[3];
    *reinterpret_cast<bf16x4*>(dst + (size_t)off * 4) = o;
}

// ---------------------------------------------------------------------------
// 256x256-tile 8-phase GEMM, QKV epilogue. n-major XCD chunking (143MB fetch).
// NO explicit lgkmcnt(0) after barriers: the ds_reads are plain loads, so the
// compiler inserts minimal counted lgkmcnt before each first MFMA use —
// letting early MFMAs overlap the tail of the LDS reads.
// ---------------------------------------------------------------------------
__global__ __launch_bounds__(512, 2) void gemm256_qkv(const bf16* __restrict__ A,
                                                      const bf16* __restrict__ B,
                                                      bf16* __restrict__ Cb,
                                                      int M, int N, int K) {
    __shared__ bf16 LA[2][256 * 64];
    __shared__ bf16 LB[2][256 * 64];
    const int tid = threadIdx.x, lane = tid & 63, wave = tid >> 6;
    const int l15 = lane & 15, lhi = lane >> 4;
    const int wr = wave >> 2, wc = wave & 3;
    const int NBY = M >> 8;                                // 16 m-tiles
    const int cpx = gridDim.x >> 3;                        // nwg % 8 == 0
    const int wg = (blockIdx.x & 7) * cpx + (blockIdx.x >> 3);
    const int m0 = (wg % NBY) * 256, n0 = (wg / NBY) * 256;   // n-major chunks
    const int NK = K >> 6;
    const int xorR = (l15 & 7) << 4;

    auto stageA = [&](int buf, int t, int h) {
        const int k0 = t << 6;
#pragma unroll
        for (int j = 0; j < 2; ++j) {
            int Xw = ((j * 128 + h * 64) << 7) + (wave << 10);
            int X = Xw + lane * 16;
            int T = X ^ (((X >> 7) & 7) << 4);
            GLOAD_LDS16(&A[(size_t)(m0 + (T >> 7)) * K + k0 + ((T & 127) >> 1)],
                        (char*)LA[buf] + Xw);
        }
    };
    auto stageB = [&](int buf, int t, int h) {
        const int k0 = t << 6;
#pragma unroll
        for (int j = 0; j < 2; ++j) {
            int base_row = h * 32 + (2 * j + (wave >> 2)) * 64;
            int Xw = (base_row << 7) + ((wave & 3) << 10);
            int X = Xw + lane * 16;
            int T = X ^ (((X >> 7) & 7) << 4);
            GLOAD_LDS16(&B[(size_t)(n0 + (T >> 7)) * K + k0 + ((T & 127) >> 1)],
                        (char*)LB[buf] + Xw);
        }
    };

    f32x4 acc[8][4] = {};

    stageA(0, 0, 0); stageB(0, 0, 0); stageB(0, 0, 1); stageA(0, 0, 1);
    stageA(1, 1, 0); stageB(1, 1, 1);
    asm volatile("s_waitcnt vmcnt(4)" ::: "memory");
    __builtin_amdgcn_s_barrier();

    bf16x8 af[4][2], bv0[2][2], bv1[2][2];

#pragma unroll 1
    for (int t = 0; t < NK; ++t) {
        const int buf = t & 1;
        char* lA = (char*)LA[buf];
        char* lB = (char*)LB[buf];

        // q0: (0,0); read A0(8)+B0(4); stage B0(t+1)
#pragma unroll
        for (int f = 0; f < 4; ++f)
#pragma unroll
            for (int ks = 0; ks < 2; ++ks) {
                int T = ((wr * 128 + f * 16 + l15) << 7) + ks * 64 + lhi * 16;
                af[f][ks] = *reinterpret_cast<const bf16x8*>(lA + (T ^ xorR));
            }
#pragma unroll
        for (int g = 0; g < 2; ++g)
#pragma unroll
            for (int ks = 0; ks < 2; ++ks) {
                int T = ((wc * 64 + g * 16 + l15) << 7) + ks * 64 + lhi * 16;
                bv0[g][ks] = *reinterpret_cast<const bf16x8*>(lB + (T ^ xorR));
            }
        if (t + 1 < NK) stageB(buf ^ 1, t + 1, 0);
        __builtin_amdgcn_s_barrier();
        __builtin_amdgcn_s_setprio(1);
#pragma unroll
        for (int f = 0; f < 4; ++f)
#pragma unroll
            for (int g = 0; g < 2; ++g)
#pragma unroll
                for (int ks = 0; ks < 2; ++ks)
                    acc[f][g] = __builtin_amdgcn_mfma_f32_16x16x32_bf16(af[f][ks], bv0[g][ks], acc[f][g], 0, 0, 0);
        __builtin_amdgcn_s_setprio(0);
        __builtin_amdgcn_s_barrier();

        // q1: (0,1); read B1(4); stage A1(t+1)
#pragma unroll
        for (int g = 0; g < 2; ++g)
#pragma unroll
            for (int ks = 0; ks < 2; ++ks) {
                int T = ((wc * 64 + 32 + g * 16 + l15) << 7) + ks * 64 + lhi * 16;
                bv1[g][ks] = *reinterpret_cast<const bf16x8*>(lB + (T ^ xorR));
            }
        if (t + 1 < NK) stageA(buf ^ 1, t + 1, 1);
        __builtin_amdgcn_s_barrier();
        __builtin_amdgcn_s_setprio(1);
#pragma unroll
        for (int f = 0; f < 4; ++f)
#pragma unroll
            for (int g = 0; g < 2; ++g)
#pragma unroll
                for (int ks = 0; ks < 2; ++ks)
                    acc[f][2 + g] = __builtin_amdgcn_mfma_f32_16x16x32_bf16(af[f][ks], bv1[g][ks], acc[f][2 + g], 0, 0, 0);
        __builtin_amdgcn_s_setprio(0);
        __builtin_amdgcn_s_barrier();

        // q2: (1,1); read A1(8); stage A0(t+2)
#pragma unroll
        for (int f = 0; f < 4; ++f)
#pragma unroll
            for (int ks = 0; ks < 2; ++ks) {
                int T = ((wr * 128 + 64 + f * 16 + l15) << 7) + ks * 64 + lhi * 16;
                af[f][ks] = *reinterpret_cast<const bf16x8*>(lA + (T ^ xorR));
            }
        if (t + 2 < NK) stageA(buf, t + 2, 0);
        __builtin_amdgcn_s_barrier();
        __builtin_amdgcn_s_setprio(1);
#pragma unroll
        for (int f = 0; f < 4; ++f)
#pragma unroll
            for (int g = 0; g < 2; ++g)
#pragma unroll
                for (int ks = 0; ks < 2; ++ks)
                    acc[4 + f][2 + g] = __builtin_amdgcn_mfma_f32_16x16x32_bf16(af[f][ks], bv1[g][ks], acc[4 + f][2 + g], 0, 0, 0);
        __builtin_amdgcn_s_setprio(0);
        __builtin_amdgcn_s_barrier();

        // q3: (1,0); no reads; stage B1(t+2)
        if (t + 2 < NK) stageB(buf, t + 2, 1);
        __builtin_amdgcn_s_barrier();
        __builtin_amdgcn_s_setprio(1);
#pragma unroll
        for (int f = 0; f < 4; ++f)
#pragma unroll
            for (int g = 0; g < 2; ++g)
#pragma unroll
                for (int ks = 0; ks < 2; ++ks)
                    acc[4 + f][g] = __builtin_amdgcn_mfma_f32_16x16x32_bf16(af[f][ks], bv0[g][ks], acc[4 + f][g], 0, 0, 0);
        __builtin_amdgcn_s_setprio(0);
        if (t + 2 == NK) {
            asm volatile("s_waitcnt vmcnt(0)" ::: "memory");
        } else if (t + 1 < NK) {
            asm volatile("s_waitcnt vmcnt(4)" ::: "memory");
        }
        __builtin_amdgcn_s_barrier();
    }

#pragma unroll
    for (int mf = 0; mf < 8; ++mf)
#pragma unroll
        for (int nf = 0; nf < 4; ++nf)
#pragma unroll
            for (int r = 0; r < 4; ++r) {
                int gm = m0 + wr * 128 + mf * 16 + lhi * 4 + r;
                int gn = n0 + wc * 64 + nf * 16 + l15;
                int proj = gn >> 11, n2 = gn & 2047;
                int b = gm >> 11, s = gm & (SS - 1);
                int h = n2 >> 7, d = n2 & (HD - 1);
                Cb[((size_t)proj << 23) + ((((size_t)(b * NH + h)) * SS + s) << 7) + d] =
                    (bf16)acc[mf][nf][r];
            }
}

// ---------------------------------------------------------------------------
// 128x128 GEMM (m97 structure), fp32 epilogue (out projection), 2D grid (R5).
// ---------------------------------------------------------------------------
__global__ __launch_bounds__(256) void gemm_bt(const bf16* __restrict__ A,
                                               const bf16* __restrict__ B,
                                               float* __restrict__ Cf,
                                               int M, int N, int K) {
    __shared__ bf16 As[128 * 64];
    __shared__ bf16 Bs[128 * 64];
    const int tid = threadIdx.x;
    const int lane = tid & 63, wave = tid >> 6;
    const int l15 = lane & 15, lhi = lane >> 4;
    const int m0 = blockIdx.y * 128, n0 = blockIdx.x * 128;
    const int wm = (wave >> 1) * 64, wn = (wave & 1) * 64;
    const int lrow = lane >> 3;
    const int lcol = (lane & 7) * 8;

    f32x4 acc[4][4] = {};

    for (int k0 = 0; k0 < K; k0 += 64) {
#pragma unroll
        for (int j = 0; j < 4; ++j) {
            const int c = wave * 4 + j;
            const int row = c * 8 + lrow;
            GLOAD_LDS16(&A[(size_t)(m0 + row) * K + k0 + lcol], &As[c * 512]);
            GLOAD_LDS16(&B[(size_t)(n0 + row) * K + k0 + lcol], &Bs[c * 512]);
        }
        __syncthreads();
#pragma unroll
        for (int ks = 0; ks < 2; ++ks) {
            bf16x8 af[4], bfr[4];
#pragma unroll
            for (int i = 0; i < 4; ++i)
                af[i] = *reinterpret_cast<const bf16x8*>(&As[(wm + i * 16 + l15) * 64 + ks * 32 + 8 * lhi]);
#pragma unroll
            for (int j = 0; j < 4; ++j)
                bfr[j] = *reinterpret_cast<const bf16x8*>(&Bs[(wn + j * 16 + l15) * 64 + ks * 32 + 8 * lhi]);
#pragma unroll
            for (int i = 0; i < 4; ++i)
#pragma unroll
                for (int j = 0; j < 4; ++j)
                    acc[i][j] = __builtin_amdgcn_mfma_f32_16x16x32_bf16(af[i], bfr[j], acc[i][j], 0, 0, 0);
        }
        __syncthreads();
    }

#pragma unroll
    for (int i = 0; i < 4; ++i)
#pragma unroll
        for (int j = 0; j < 4; ++j)
#pragma unroll
            for (int r = 0; r < 4; ++r) {
                int gm = m0 + wm + i * 16 + lhi * 4 + r;
                int gn = n0 + wn + j * 16 + l15;
                Cf[(size_t)gm * N + gn] = acc[i][j][r];
            }
}

// ---------------------------------------------------------------------------
// Merged RoPE + V-transpose (one launch, two block ranges).
// Blocks [0, 2048): RoPE on Q,K. Blocks [2048, 4096): Vh -> Vt[head][d][s].
// ---------------------------------------------------------------------------
__global__ __launch_bounds__(256) void rope_tv(bf16* __restrict__ Qh,
                                               bf16* __restrict__ Kh,
                                               const float* __restrict__ cosT,
                                               const float* __restrict__ sinT,
                                               const bf16* __restrict__ Vh,
                                               bf16* __restrict__ Vt) {
    __shared__ bf16 T[64 * 64];
    const int tid = threadIdx.x;
    if (blockIdx.x < 2048) {
        int idx = blockIdx.x * 256 + tid;
        int g = idx & 7;
        int s = (idx >> 3) & (SS - 1);
        int head = idx >> 14;
        int d0 = g * 8;
        size_t base = ((size_t)head * SS + s) * HD;
        f32x4 ca = *reinterpret_cast<const f32x4*>(&cosT[s * HD + d0]);
        f32x4 cb = *reinterpret_cast<const f32x4*>(&cosT[s * HD + d0 + 4]);
        f32x4 sa = *reinterpret_cast<const f32x4*>(&sinT[s * HD + d0]);
        f32x4 sb = *reinterpret_cast<const f32x4*>(&sinT[s * HD + d0 + 4]);
        bf16x8 ql = *reinterpret_cast<const bf16x8*>(&Qh[base + d0]);
        bf16x8 qh = *reinterpret_cast<const bf16x8*>(&Qh[base + 64 + d0]);
        bf16x8 kl = *reinterpret_cast<const bf16x8*>(&Kh[base + d0]);
        bf16x8 kh = *reinterpret_cast<const bf16x8*>(&Kh[base + 64 + d0]);
        bf16x8 qlo, qhi, klo, khi;
#pragma unroll
        for (int j = 0; j < 8; ++j) {
            float c = (j < 4) ? ca[j] : cb[j - 4];
            float sn = (j < 4) ? sa[j] : sb[j - 4];
            float q0 = (float)ql[j], q1 = (float)qh[j];
            float k0 = (float)kl[j], k1 = (float)kh[j];
            qlo[j] = (bf16)(q0 * c - q1 * sn);
            qhi[j] = (bf16)(q1 * c + q0 * sn);
            klo[j] = (bf16)(k0 * c - k1 * sn);
            khi[j] = (bf16)(k1 * c + k0 * sn);
        }
        *reinterpret_cast<bf16x8*>(&Qh[base + d0]) = qlo;
        *reinterpret_cast<bf16x8*>(&Qh[base + 64 + d0]) = qhi;
        *reinterpret_cast<bf16x8*>(&Kh[base + d0]) = klo;
        *reinterpret_cast<bf16x8*>(&Kh[base + 64 + d0]) = khi;
    } else {
        const int b2 = blockIdx.x - 2048;
        const int s0 = (b2 & 31) * 64;
        const int d0 = ((b2 >> 5) & 1) * 64;
        const int head = b2 >> 6;
        const bf16* src = Vh + ((size_t)head * SS) * HD;
        bf16* dst = Vt + ((size_t)head * HD) * SS;

#pragma unroll
        for (int i = 0; i < 2; ++i) {
            int id = tid + i * 256;
            int r = id >> 3, c16 = id & 7;
            bf16x8 v = *reinterpret_cast<const bf16x8*>(&src[(size_t)(s0 + r) * HD + d0 + c16 * 8]);
            int sw = c16 ^ ((r ^ (r >> 3)) & 7);
            *reinterpret_cast<bf16x8*>((char*)T + r * 128 + sw * 16) = v;
        }
        __syncthreads();
#pragma unroll
        for (int i = 0; i < 2; ++i) {
            int id = tid + i * 256;
            int dr = id >> 3, sc8 = (id & 7) * 8;
            bf16x8 o;
#pragma unroll
            for (int j = 0; j < 8; ++j) {
                int r = sc8 + j;
                int sw = (dr >> 3) ^ ((r ^ (r >> 3)) & 7);
                o[j] = *reinterpret_cast<const bf16*>((char*)T + r * 128 + sw * 16 + (dr & 7) * 2);
            }
            *reinterpret_cast<bf16x8*>(&dst[(size_t)(d0 + dr) * SS + s0 + sc8]) = o;
        }
    }
}

// ---------------------------------------------------------------------------
// Causal flash attention (R5 proven version): load-balanced pairs, K/V
// double-buffered, XOR-swizzled, defer-max. grid 512, block 256 (4 waves).
// ---------------------------------------------------------------------------
__global__ __launch_bounds__(256) void attn_kernel(const bf16* __restrict__ Q,
                                                   const bf16* __restrict__ K,
                                                   const bf16* __restrict__ Vt,
                                                   bf16* __restrict__ Ob) {
    __shared__ bf16 Ks[2][64 * 128];
    __shared__ bf16 Vs[2][128 * 64];
    __shared__ bf16 Ps[4][16][72];

    const int tid = threadIdx.x, lane = tid & 63, wave = tid >> 6;
    const int l15 = lane & 15, lhi = lane >> 4;
    const int bid = blockIdx.x;
    const int orig = (bid & 7) * 64 + (bid >> 3);   // XCD swizzle
    const int head = orig >> 4;
    const int pi = orig & 15;
    const int b = head >> 4, h = head & (NH - 1);
    const size_t hb = (size_t)head * SS * HD;
    const bf16* Vth = Vt + (size_t)head * HD * SS;
    const float cexp = 0.08838834764831845f * 1.4426950408889634f;
    const float THR = 62.0f;

#pragma unroll 1
    for (int part = 0; part < 2; ++part) {
        const int t = part ? (31 - pi) : pi;
        const int q0 = t * 64;
        const int qw = q0 + wave * 16;
        const int nkv = t + 1;

        bf16x8 qf[4];
#pragma unroll
        for (int ks = 0; ks < 4; ++ks)
            qf[ks] = *reinterpret_cast<const bf16x8*>(
                &Q[hb + (size_t)(qw + l15) * HD + ks * 32 + 8 * lhi]);

        f32x4 oacc[8] = {};
        float Mr[4], Lp[4];
#pragma unroll
        for (int r = 0; r < 4; ++r) { Mr[r] = -INFINITY; Lp[r] = 0.f; }

        bf16x8 kr[4], vr[4];
#pragma unroll
        for (int i = 0; i < 4; ++i) {
            int id = tid + i * 256;
            kr[i] = *reinterpret_cast<const bf16x8*>(&K[hb + (size_t)(id >> 4) * HD + (id & 15) * 8]);
            vr[i] = *reinterpret_cast<const bf16x8*>(&Vth[(size_t)(id >> 3) * SS + (id & 7) * 8]);
        }
#pragma unroll
        for (int i = 0; i < 4; ++i) {
            int id = tid + i * 256;
            int krow = id >> 4, kc = id & 15;
            *reinterpret_cast<bf16x8*>((char*)Ks[0] + ((krow * 256 + kc * 16) ^ ((krow & 7) << 4))) = kr[i];
            int vrow = id >> 3, vc = id & 7;
            *reinterpret_cast<bf16x8*>((char*)Vs[0] + ((vrow * 128 + vc * 16) ^ ((vrow & 7) << 4))) = vr[i];
        }
        __syncthreads();

        for (int it = 0; it < nkv; ++it) {
            const int cur = it & 1;
            const bool pre = (it + 1 < nkv);
            if (pre) {
                const int kv0 = (it + 1) * 64;
#pragma unroll
                for (int i = 0; i < 4; ++i) {
                    int id = tid + i * 256;
                    kr[i] = *reinterpret_cast<const bf16x8*>(&K[hb + (size_t)(kv0 + (id >> 4)) * HD + (id & 15) * 8]);
                    vr[i] = *reinterpret_cast<const bf16x8*>(&Vth[(size_t)(id >> 3) * SS + kv0 + (id & 7) * 8]);
                }
            }

            f32x4 sf[4] = {};
#pragma unroll
            for (int ks = 0; ks < 4; ++ks) {
#pragma unroll
                for (int ne = 0; ne < 4; ++ne) {
                    int row = ne * 16 + l15;
                    bf16x8 kf = *reinterpret_cast<const bf16x8*>(
                        (const char*)Ks[cur] + ((row * 256 + (ks * 4 + lhi) * 16) ^ ((row & 7) << 4)));
                    sf[ne] = __builtin_amdgcn_mfma_f32_16x16x32_bf16(qf[ks], kf, sf[ne], 0, 0, 0);
                }
            }

            if (it == nkv - 1) {
#pragma unroll
                for (int ne = 0; ne < 4; ++ne)
#pragma unroll
                    for (int r = 0; r < 4; ++r) {
                        int gq = qw + lhi * 4 + r;
                        int gk = it * 64 + ne * 16 + l15;
                        if (gk > gq) sf[ne][r] = -INFINITY;
                    }
            }

            float lm[4];
#pragma unroll
            for (int r = 0; r < 4; ++r)
                lm[r] = fmaxf(fmaxf(sf[0][r], sf[1][r]), fmaxf(sf[2][r], sf[3][r]));
            bool need = (lm[0] > Mr[0] + THR) || (lm[1] > Mr[1] + THR) ||
                        (lm[2] > Mr[2] + THR) || (lm[3] > Mr[3] + THR);
            if (__any(need)) {
                float rmax[4] = {lm[0], lm[1], lm[2], lm[3]};
#pragma unroll
                for (int m = 1; m < 16; m <<= 1)
#pragma unroll
                    for (int r = 0; r < 4; ++r)
                        rmax[r] = fmaxf(rmax[r], __shfl_xor(rmax[r], m));
#pragma unroll
                for (int r = 0; r < 4; ++r) {
                    float nM = fmaxf(Mr[r], rmax[r]);
                    float scf = __builtin_amdgcn_exp2f((Mr[r] - nM) * cexp);
                    Mr[r] = nM;
                    Lp[r] *= scf;
#pragma unroll
                    for (int nf = 0; nf < 8; ++nf) oacc[nf][r] *= scf;
                }
            }
#pragma unroll
            for (int ne = 0; ne < 4; ++ne)
#pragma unroll
                for (int r = 0; r < 4; ++r) {
                    float p = __builtin_amdgcn_exp2f((sf[ne][r] - Mr[r]) * cexp);
                    Lp[r] += p;
                    Ps[wave][lhi * 4 + r][ne * 16 + l15] = (bf16)p;
                }

#pragma unroll
            for (int ks = 0; ks < 2; ++ks) {
                bf16x8 pa = *reinterpret_cast<const bf16x8*>(&Ps[wave][l15][ks * 32 + 8 * lhi]);
#pragma unroll
                for (int nf = 0; nf < 8; ++nf) {
                    int row = nf * 16 + l15;
                    bf16x8 vb = *reinterpret_cast<const bf16x8*>(
                        (const char*)Vs[cur] + ((row * 128 + (ks * 4 + lhi) * 16) ^ ((row & 7) << 4)));
                    oacc[nf] = __builtin_amdgcn_mfma_f32_16x16x32_bf16(pa, vb, oacc[nf], 0, 0, 0);
                }
            }

            if (pre) {
#pragma unroll
                for (int i = 0; i < 4; ++i) {
                    int id = tid + i * 256;
                    int krow = id >> 4, kc = id & 15;
                    *reinterpret_cast<bf16x8*>((char*)Ks[cur ^ 1] + ((krow * 256 + kc * 16) ^ ((krow & 7) << 4))) = kr[i];
                    int vrow = id >> 3, vc = id & 7;
                    *reinterpret_cast<bf16x8*>((char*)Vs[cur ^ 1] + ((vrow * 128 + vc * 16) ^ ((vrow & 7) << 4))) = vr[i];
                }
            }
            __syncthreads();
        }

#pragma unroll
        for (int m = 1; m < 16; m <<= 1)
#pragma unroll
            for (int r = 0; r < 4; ++r)
                Lp[r] += __shfl_xor(Lp[r], m);
        float inv[4];
#pragma unroll
        for (int r = 0; r < 4; ++r) inv[r] = 1.f / Lp[r];
#pragma unroll
        for (int nf = 0; nf < 8; ++nf)
#pragma unroll
            for (int r = 0; r < 4; ++r) {
                int s = qw + lhi * 4 + r;
                int d = nf * 16 + l15;
                Ob[((size_t)(b * SS + s)) * HH + h * HD + d] = (bf16)(oacc[nf][r] * inv[r]);
            }
    }
}

// ---------------------------------------------------------------------------
extern "C" void kernel_launch(void* const* d_in, const int* in_sizes, int n_in,
                              void* d_out, int out_size, void* d_ws, size_t ws_size,
                              hipStream_t stream) {
    const float* hs   = (const float*)d_in[0];
    const float* cosT = (const float*)d_in[2];
    const float* sinT = (const float*)d_in[3];
    const float* Wq   = (const float*)d_in[4];
    const float* Wk   = (const float*)d_in[5];
    const float* Wv   = (const float*)d_in[6];
    const float* Wo   = (const float*)d_in[7];
    float* out = (float*)d_out;

    char* w = (char*)d_ws;
    auto alloc = [&](size_t bytes) {
        char* p = w;
        w += (bytes + 255) & ~(size_t)255;
        return p;
    };
    const size_t XE = (size_t)BB * SS * HH;
    const size_t WE = (size_t)HH * HH;
    bf16* Xb   = (bf16*)alloc(XE * 2);
    bf16* Wqkv = (bf16*)alloc(3 * WE * 2);
    bf16* Wob  = (bf16*)alloc(WE * 2);
    bf16* QKV  = (bf16*)alloc(3 * XE * 2);
    bf16* Vtg  = (bf16*)alloc(XE * 2);
    bf16* Ob   = (bf16*)alloc(XE * 2);

    const int M = BB * SS;  // 4096
    bf16* Qh = QKV;
    bf16* Kh = QKV + XE;
    bf16* Vh = QKV + 2 * XE;

    {
        int total4 = (int)((XE + 4 * WE) / 4);
        cast_all<<<(total4 + 255) / 256, 256, 0, stream>>>(hs, Wq, Wk, Wv, Wo, Xb, Wqkv, Wob);
    }

    // fused QKV projection: M=4096, N=6144, K=2048, 256^2 8-phase, n-major XCD
    gemm256_qkv<<<dim3((M / 256) * (3 * HH / 256)), 512, 0, stream>>>(Xb, Wqkv, QKV, M, 3 * HH, HH);

    // merged RoPE (Q,K) + V transpose
    rope_tv<<<4096, 256, 0, stream>>>(Qh, Kh, cosT, sinT, Vh, Vtg);

    attn_kernel<<<512, 256, 0, stream>>>(Qh, Kh, Vtg, Ob);

    // out projection: M=4096, N=2048, K=2048, 2D grid (R5 config)
    dim3 ogrid(HH / 128, M / 128);
    gemm_bt<<<ogrid, 256, 0, stream>>>(Ob, Wob, out, M, HH, HH);
}

// Round 10
// 273.769 us; speedup vs baseline: 1.2688x; 1.0900x over previous
//
#include <hip/hip_runtime.h>
#include <hip/hip_bf16.h>

typedef __bf16 bf16;
typedef __attribute__((ext_vector_type(8))) __bf16 bf16x8;
typedef __attribute__((ext_vector_type(4))) __bf16 bf16x4;
typedef __attribute__((ext_vector_type(4))) float f32x4;

// Problem constants
#define BB 2
#define SS 2048
#define HH 2048
#define NH 16
#define HD 128

#define GLOAD_LDS16(g, l)                                                  \
    __builtin_amdgcn_global_load_lds(                                      \
        (const __attribute__((address_space(1))) void*)(g),                \
        (__attribute__((address_space(3))) void*)(l), 16, 0, 0)

// ---------------------------------------------------------------------------
// Batched fp32 -> bf16 cast: X then Wq,Wk,Wv (into contiguous Wqkv), Wo.
// ---------------------------------------------------------------------------
__global__ __launch_bounds__(256) void cast_all(const float* __restrict__ hs,
                                                const float* __restrict__ Wq,
                                                const float* __restrict__ Wk,
                                                const float* __restrict__ Wv,
                                                const float* __restrict__ Wo,
                                                bf16* __restrict__ Xb,
                                                bf16* __restrict__ Wqkv,
                                                bf16* __restrict__ Wob) {
    const int XE4 = (BB * SS * HH) / 4;
    const int WE4 = (HH * HH) / 4;
    int i = blockIdx.x * 256 + threadIdx.x;
    const float* src;
    bf16* dst;
    int off;
    if (i < XE4) { src = hs; dst = Xb; off = i; }
    else if (i < XE4 + WE4) { src = Wq; dst = Wqkv; off = i - XE4; }
    else if (i < XE4 + 2 * WE4) { src = Wk; dst = Wqkv + (size_t)HH * HH; off = i - XE4 - WE4; }
    else if (i < XE4 + 3 * WE4) { src = Wv; dst = Wqkv + 2 * (size_t)HH * HH; off = i - XE4 - 2 * WE4; }
    else { src = Wo; dst = Wob; off = i - XE4 - 3 * WE4; }
    f32x4 v = *reinterpret_cast<const f32x4*>(src + (size_t)off * 4);
    bf16x4 o;
    o[0] = (bf16)v[0]; o[1] = (bf16)v[1]; o[2] = (bf16)v[2]; o[3] = (bf16)v[3];
    *reinterpret_cast<bf16x4*>(dst + (size_t)off * 4) = o;
}

// ---------------------------------------------------------------------------
// 256x256-tile 8-phase GEMM, QKV epilogue (R9 version, 131 us).
// ---------------------------------------------------------------------------
__global__ __launch_bounds__(512, 2) void gemm256_qkv(const bf16* __restrict__ A,
                                                      const bf16* __restrict__ B,
                                                      bf16* __restrict__ Cb,
                                                      int M, int N, int K) {
    __shared__ bf16 LA[2][256 * 64];
    __shared__ bf16 LB[2][256 * 64];
    const int tid = threadIdx.x, lane = tid & 63, wave = tid >> 6;
    const int l15 = lane & 15, lhi = lane >> 4;
    const int wr = wave >> 2, wc = wave & 3;
    const int NBY = M >> 8;
    const int cpx = gridDim.x >> 3;
    const int wg = (blockIdx.x & 7) * cpx + (blockIdx.x >> 3);
    const int m0 = (wg % NBY) * 256, n0 = (wg / NBY) * 256;
    const int NK = K >> 6;
    const int xorR = (l15 & 7) << 4;

    auto stageA = [&](int buf, int t, int h) {
        const int k0 = t << 6;
#pragma unroll
        for (int j = 0; j < 2; ++j) {
            int Xw = ((j * 128 + h * 64) << 7) + (wave << 10);
            int X = Xw + lane * 16;
            int T = X ^ (((X >> 7) & 7) << 4);
            GLOAD_LDS16(&A[(size_t)(m0 + (T >> 7)) * K + k0 + ((T & 127) >> 1)],
                        (char*)LA[buf] + Xw);
        }
    };
    auto stageB = [&](int buf, int t, int h) {
        const int k0 = t << 6;
#pragma unroll
        for (int j = 0; j < 2; ++j) {
            int base_row = h * 32 + (2 * j + (wave >> 2)) * 64;
            int Xw = (base_row << 7) + ((wave & 3) << 10);
            int X = Xw + lane * 16;
            int T = X ^ (((X >> 7) & 7) << 4);
            GLOAD_LDS16(&B[(size_t)(n0 + (T >> 7)) * K + k0 + ((T & 127) >> 1)],
                        (char*)LB[buf] + Xw);
        }
    };

    f32x4 acc[8][4] = {};

    stageA(0, 0, 0); stageB(0, 0, 0); stageB(0, 0, 1); stageA(0, 0, 1);
    stageA(1, 1, 0); stageB(1, 1, 1);
    asm volatile("s_waitcnt vmcnt(4)" ::: "memory");
    __builtin_amdgcn_s_barrier();

    bf16x8 af[4][2], bv0[2][2], bv1[2][2];

#pragma unroll 1
    for (int t = 0; t < NK; ++t) {
        const int buf = t & 1;
        char* lA = (char*)LA[buf];
        char* lB = (char*)LB[buf];

        // q0
#pragma unroll
        for (int f = 0; f < 4; ++f)
#pragma unroll
            for (int ks = 0; ks < 2; ++ks) {
                int T = ((wr * 128 + f * 16 + l15) << 7) + ks * 64 + lhi * 16;
                af[f][ks] = *reinterpret_cast<const bf16x8*>(lA + (T ^ xorR));
            }
#pragma unroll
        for (int g = 0; g < 2; ++g)
#pragma unroll
            for (int ks = 0; ks < 2; ++ks) {
                int T = ((wc * 64 + g * 16 + l15) << 7) + ks * 64 + lhi * 16;
                bv0[g][ks] = *reinterpret_cast<const bf16x8*>(lB + (T ^ xorR));
            }
        if (t + 1 < NK) stageB(buf ^ 1, t + 1, 0);
        __builtin_amdgcn_s_barrier();
        __builtin_amdgcn_s_setprio(1);
#pragma unroll
        for (int f = 0; f < 4; ++f)
#pragma unroll
            for (int g = 0; g < 2; ++g)
#pragma unroll
                for (int ks = 0; ks < 2; ++ks)
                    acc[f][g] = __builtin_amdgcn_mfma_f32_16x16x32_bf16(af[f][ks], bv0[g][ks], acc[f][g], 0, 0, 0);
        __builtin_amdgcn_s_setprio(0);
        __builtin_amdgcn_s_barrier();

        // q1
#pragma unroll
        for (int g = 0; g < 2; ++g)
#pragma unroll
            for (int ks = 0; ks < 2; ++ks) {
                int T = ((wc * 64 + 32 + g * 16 + l15) << 7) + ks * 64 + lhi * 16;
                bv1[g][ks] = *reinterpret_cast<const bf16x8*>(lB + (T ^ xorR));
            }
        if (t + 1 < NK) stageA(buf ^ 1, t + 1, 1);
        __builtin_amdgcn_s_barrier();
        __builtin_amdgcn_s_setprio(1);
#pragma unroll
        for (int f = 0; f < 4; ++f)
#pragma unroll
            for (int g = 0; g < 2; ++g)
#pragma unroll
                for (int ks = 0; ks < 2; ++ks)
                    acc[f][2 + g] = __builtin_amdgcn_mfma_f32_16x16x32_bf16(af[f][ks], bv1[g][ks], acc[f][2 + g], 0, 0, 0);
        __builtin_amdgcn_s_setprio(0);
        __builtin_amdgcn_s_barrier();

        // q2
#pragma unroll
        for (int f = 0; f < 4; ++f)
#pragma unroll
            for (int ks = 0; ks < 2; ++ks) {
                int T = ((wr * 128 + 64 + f * 16 + l15) << 7) + ks * 64 + lhi * 16;
                af[f][ks] = *reinterpret_cast<const bf16x8*>(lA + (T ^ xorR));
            }
        if (t + 2 < NK) stageA(buf, t + 2, 0);
        __builtin_amdgcn_s_barrier();
        __builtin_amdgcn_s_setprio(1);
#pragma unroll
        for (int f = 0; f < 4; ++f)
#pragma unroll
            for (int g = 0; g < 2; ++g)
#pragma unroll
                for (int ks = 0; ks < 2; ++ks)
                    acc[4 + f][2 + g] = __builtin_amdgcn_mfma_f32_16x16x32_bf16(af[f][ks], bv1[g][ks], acc[4 + f][2 + g], 0, 0, 0);
        __builtin_amdgcn_s_setprio(0);
        __builtin_amdgcn_s_barrier();

        // q3
        if (t + 2 < NK) stageB(buf, t + 2, 1);
        __builtin_amdgcn_s_barrier();
        __builtin_amdgcn_s_setprio(1);
#pragma unroll
        for (int f = 0; f < 4; ++f)
#pragma unroll
            for (int g = 0; g < 2; ++g)
#pragma unroll
                for (int ks = 0; ks < 2; ++ks)
                    acc[4 + f][g] = __builtin_amdgcn_mfma_f32_16x16x32_bf16(af[f][ks], bv0[g][ks], acc[4 + f][g], 0, 0, 0);
        __builtin_amdgcn_s_setprio(0);
        if (t + 2 == NK) {
            asm volatile("s_waitcnt vmcnt(0)" ::: "memory");
        } else if (t + 1 < NK) {
            asm volatile("s_waitcnt vmcnt(4)" ::: "memory");
        }
        __builtin_amdgcn_s_barrier();
    }

#pragma unroll
    for (int mf = 0; mf < 8; ++mf)
#pragma unroll
        for (int nf = 0; nf < 4; ++nf)
#pragma unroll
            for (int r = 0; r < 4; ++r) {
                int gm = m0 + wr * 128 + mf * 16 + lhi * 4 + r;
                int gn = n0 + wc * 64 + nf * 16 + l15;
                int proj = gn >> 11, n2 = gn & 2047;
                int b = gm >> 11, s = gm & (SS - 1);
                int h = n2 >> 7, d = n2 & (HD - 1);
                Cb[((size_t)proj << 23) + ((((size_t)(b * NH + h)) * SS + s) << 7) + d] =
                    (bf16)acc[mf][nf][r];
            }
}

// ---------------------------------------------------------------------------
// 128x128 GEMM (m97 structure), fp32 epilogue (out projection), 2D grid.
// ---------------------------------------------------------------------------
__global__ __launch_bounds__(256) void gemm_bt(const bf16* __restrict__ A,
                                               const bf16* __restrict__ B,
                                               float* __restrict__ Cf,
                                               int M, int N, int K) {
    __shared__ bf16 As[128 * 64];
    __shared__ bf16 Bs[128 * 64];
    const int tid = threadIdx.x;
    const int lane = tid & 63, wave = tid >> 6;
    const int l15 = lane & 15, lhi = lane >> 4;
    const int m0 = blockIdx.y * 128, n0 = blockIdx.x * 128;
    const int wm = (wave >> 1) * 64, wn = (wave & 1) * 64;
    const int lrow = lane >> 3;
    const int lcol = (lane & 7) * 8;

    f32x4 acc[4][4] = {};

    for (int k0 = 0; k0 < K; k0 += 64) {
#pragma unroll
        for (int j = 0; j < 4; ++j) {
            const int c = wave * 4 + j;
            const int row = c * 8 + lrow;
            GLOAD_LDS16(&A[(size_t)(m0 + row) * K + k0 + lcol], &As[c * 512]);
            GLOAD_LDS16(&B[(size_t)(n0 + row) * K + k0 + lcol], &Bs[c * 512]);
        }
        __syncthreads();
#pragma unroll
        for (int ks = 0; ks < 2; ++ks) {
            bf16x8 af[4], bfr[4];
#pragma unroll
            for (int i = 0; i < 4; ++i)
                af[i] = *reinterpret_cast<const bf16x8*>(&As[(wm + i * 16 + l15) * 64 + ks * 32 + 8 * lhi]);
#pragma unroll
            for (int j = 0; j < 4; ++j)
                bfr[j] = *reinterpret_cast<const bf16x8*>(&Bs[(wn + j * 16 + l15) * 64 + ks * 32 + 8 * lhi]);
#pragma unroll
            for (int i = 0; i < 4; ++i)
#pragma unroll
                for (int j = 0; j < 4; ++j)
                    acc[i][j] = __builtin_amdgcn_mfma_f32_16x16x32_bf16(af[i], bfr[j], acc[i][j], 0, 0, 0);
        }
        __syncthreads();
    }

#pragma unroll
    for (int i = 0; i < 4; ++i)
#pragma unroll
        for (int j = 0; j < 4; ++j)
#pragma unroll
            for (int r = 0; r < 4; ++r) {
                int gm = m0 + wm + i * 16 + lhi * 4 + r;
                int gn = n0 + wn + j * 16 + l15;
                Cf[(size_t)gm * N + gn] = acc[i][j][r];
            }
}

// ---------------------------------------------------------------------------
// Merged RoPE + V-transpose (one launch, two block ranges).
// ---------------------------------------------------------------------------
__global__ __launch_bounds__(256) void rope_tv(bf16* __restrict__ Qh,
                                               bf16* __restrict__ Kh,
                                               const float* __restrict__ cosT,
                                               const float* __restrict__ sinT,
                                               const bf16* __restrict__ Vh,
                                               bf16* __restrict__ Vt) {
    __shared__ bf16 T[64 * 64];
    const int tid = threadIdx.x;
    if (blockIdx.x < 2048) {
        int idx = blockIdx.x * 256 + tid;
        int g = idx & 7;
        int s = (idx >> 3) & (SS - 1);
        int head = idx >> 14;
        int d0 = g * 8;
        size_t base = ((size_t)head * SS + s) * HD;
        f32x4 ca = *reinterpret_cast<const f32x4*>(&cosT[s * HD + d0]);
        f32x4 cb = *reinterpret_cast<const f32x4*>(&cosT[s * HD + d0 + 4]);
        f32x4 sa = *reinterpret_cast<const f32x4*>(&sinT[s * HD + d0]);
        f32x4 sb = *reinterpret_cast<const f32x4*>(&sinT[s * HD + d0 + 4]);
        bf16x8 ql = *reinterpret_cast<const bf16x8*>(&Qh[base + d0]);
        bf16x8 qh = *reinterpret_cast<const bf16x8*>(&Qh[base + 64 + d0]);
        bf16x8 kl = *reinterpret_cast<const bf16x8*>(&Kh[base + d0]);
        bf16x8 kh = *reinterpret_cast<const bf16x8*>(&Kh[base + 64 + d0]);
        bf16x8 qlo, qhi, klo, khi;
#pragma unroll
        for (int j = 0; j < 8; ++j) {
            float c = (j < 4) ? ca[j] : cb[j - 4];
            float sn = (j < 4) ? sa[j] : sb[j - 4];
            float q0 = (float)ql[j], q1 = (float)qh[j];
            float k0 = (float)kl[j], k1 = (float)kh[j];
            qlo[j] = (bf16)(q0 * c - q1 * sn);
            qhi[j] = (bf16)(q1 * c + q0 * sn);
            klo[j] = (bf16)(k0 * c - k1 * sn);
            khi[j] = (bf16)(k1 * c + k0 * sn);
        }
        *reinterpret_cast<bf16x8*>(&Qh[base + d0]) = qlo;
        *reinterpret_cast<bf16x8*>(&Qh[base + 64 + d0]) = qhi;
        *reinterpret_cast<bf16x8*>(&Kh[base + d0]) = klo;
        *reinterpret_cast<bf16x8*>(&Kh[base + 64 + d0]) = khi;
    } else {
        const int b2 = blockIdx.x - 2048;
        const int s0 = (b2 & 31) * 64;
        const int d0 = ((b2 >> 5) & 1) * 64;
        const int head = b2 >> 6;
        const bf16* src = Vh + ((size_t)head * SS) * HD;
        bf16* dst = Vt + ((size_t)head * HD) * SS;

#pragma unroll
        for (int i = 0; i < 2; ++i) {
            int id = tid + i * 256;
            int r = id >> 3, c16 = id & 7;
            bf16x8 v = *reinterpret_cast<const bf16x8*>(&src[(size_t)(s0 + r) * HD + d0 + c16 * 8]);
            int sw = c16 ^ ((r ^ (r >> 3)) & 7);
            *reinterpret_cast<bf16x8*>((char*)T + r * 128 + sw * 16) = v;
        }
        __syncthreads();
#pragma unroll
        for (int i = 0; i < 2; ++i) {
            int id = tid + i * 256;
            int dr = id >> 3, sc8 = (id & 7) * 8;
            bf16x8 o;
#pragma unroll
            for (int j = 0; j < 8; ++j) {
                int r = sc8 + j;
                int sw = (dr >> 3) ^ ((r ^ (r >> 3)) & 7);
                o[j] = *reinterpret_cast<const bf16*>((char*)T + r * 128 + sw * 16 + (dr & 7) * 2);
            }
            *reinterpret_cast<bf16x8*>(&dst[(size_t)(d0 + dr) * SS + s0 + sc8]) = o;
        }
    }
}

// ---------------------------------------------------------------------------
// Causal flash attention, QB=128, 8 waves x 16 q-rows, KVBLK=64.
// K/V double-buffered, staged via global_load_lds (linear dest +
// inverse-swizzled global source + swizzled ds_read). One barrier per iter;
// next tile's loads issued at iter top, drained (vmcnt 0) at iter bottom.
// Grid 256 = 32 heads x 8 pairs (T, 15-T): uniform 34 iters/block.
// ---------------------------------------------------------------------------
__global__ __launch_bounds__(512) void attn_kernel(const bf16* __restrict__ Q,
                                                   const bf16* __restrict__ K,
                                                   const bf16* __restrict__ Vt,
                                                   bf16* __restrict__ Ob) {
    __shared__ bf16 Ks[2][64 * 128];   // 32 KiB, row stride 256B, swz bit8->bit4
    __shared__ bf16 Vs[2][128 * 64];   // 32 KiB, row stride 128B, swz bit7->bit4
    __shared__ bf16 Ps[8][16 * 72];    // 18 KiB

    const int tid = threadIdx.x, lane = tid & 63, wave = tid >> 6;
    const int l15 = lane & 15, lhi = lane >> 4;
    const int bid = blockIdx.x;
    const int orig = (bid & 7) * 32 + (bid >> 3);   // XCD swizzle (256 % 8 == 0)
    const int head = orig >> 3;
    const int pi = orig & 7;
    const int b = head >> 4, h = head & (NH - 1);
    const size_t hb = (size_t)head * SS * HD;
    const bf16* Vth = Vt + (size_t)head * HD * SS;
    const float cexp = 0.08838834764831845f * 1.4426950408889634f;
    const float THR = 62.0f;

    // stage K+V tile at kv0 into buffer buf (4 global_load_lds per thread)
    auto stageKV = [&](int buf, int kv0) {
#pragma unroll
        for (int j = 0; j < 2; ++j) {
            int Xw = (j * 8 + wave) << 10;
            int X = Xw + lane * 16;
            int T = X ^ (((X >> 8) & 7) << 4);     // K: row bits at 8+
            GLOAD_LDS16(&K[hb + (size_t)(kv0 + (T >> 8)) * HD + ((T & 255) >> 1)],
                        (char*)Ks[buf] + Xw);
        }
#pragma unroll
        for (int j = 0; j < 2; ++j) {
            int Xw = (j * 8 + wave) << 10;
            int X = Xw + lane * 16;
            int T = X ^ (((X >> 7) & 7) << 4);     // V: row bits at 7+
            GLOAD_LDS16(&Vth[(size_t)(T >> 7) * SS + kv0 + ((T & 127) >> 1)],
                        (char*)Vs[buf] + Xw);
        }
    };

#pragma unroll 1
    for (int part = 0; part < 2; ++part) {
        const int t = part ? (15 - pi) : pi;
        const int q0 = t * 128;
        const int qw = q0 + wave * 16;
        const int nkv = 2 * t + 2;

        bf16x8 qf[4];
#pragma unroll
        for (int ks = 0; ks < 4; ++ks)
            qf[ks] = *reinterpret_cast<const bf16x8*>(
                &Q[hb + (size_t)(qw + l15) * HD + ks * 32 + 8 * lhi]);

        f32x4 oacc[8] = {};
        float Mr[4], Lp[4];
#pragma unroll
        for (int r = 0; r < 4; ++r) { Mr[r] = -INFINITY; Lp[r] = 0.f; }

        // prologue: stage tile 0
        stageKV(0, 0);
        asm volatile("s_waitcnt vmcnt(0)" ::: "memory");
        __builtin_amdgcn_s_barrier();

        for (int it = 0; it < nkv; ++it) {
            const int cur = it & 1;
            // issue next tile's loads into the freed buffer
            if (it + 1 < nkv) stageKV(cur ^ 1, (it + 1) * 64);

            // ---- S = Q K^T from Ks[cur] ----
            f32x4 sf[4] = {};
#pragma unroll
            for (int ks = 0; ks < 4; ++ks) {
#pragma unroll
                for (int ne = 0; ne < 4; ++ne) {
                    int row = ne * 16 + l15;
                    bf16x8 kf = *reinterpret_cast<const bf16x8*>(
                        (const char*)Ks[cur] + ((row * 256 + (ks * 4 + lhi) * 16) ^ ((row & 7) << 4)));
                    sf[ne] = __builtin_amdgcn_mfma_f32_16x16x32_bf16(qf[ks], kf, sf[ne], 0, 0, 0);
                }
            }

            // causal mask: last two kv-tiles intersect the diagonal band
            if (it >= nkv - 2) {
#pragma unroll
                for (int ne = 0; ne < 4; ++ne)
#pragma unroll
                    for (int r = 0; r < 4; ++r) {
                        int gq = qw + lhi * 4 + r;
                        int gk = it * 64 + ne * 16 + l15;
                        if (gk > gq) sf[ne][r] = -INFINITY;
                    }
            }

            // ---- defer-max online softmax ----
            float lm[4];
#pragma unroll
            for (int r = 0; r < 4; ++r)
                lm[r] = fmaxf(fmaxf(sf[0][r], sf[1][r]), fmaxf(sf[2][r], sf[3][r]));
            bool need = (lm[0] > Mr[0] + THR) || (lm[1] > Mr[1] + THR) ||
                        (lm[2] > Mr[2] + THR) || (lm[3] > Mr[3] + THR);
            if (__any(need)) {
                float rmax[4] = {lm[0], lm[1], lm[2], lm[3]};
#pragma unroll
                for (int m = 1; m < 16; m <<= 1)
#pragma unroll
                    for (int r = 0; r < 4; ++r)
                        rmax[r] = fmaxf(rmax[r], __shfl_xor(rmax[r], m));
#pragma unroll
                for (int r = 0; r < 4; ++r) {
                    float nM = fmaxf(Mr[r], rmax[r]);
                    float scf = __builtin_amdgcn_exp2f((Mr[r] - nM) * cexp);
                    Mr[r] = nM;
                    Lp[r] *= scf;
#pragma unroll
                    for (int nf = 0; nf < 8; ++nf) oacc[nf][r] *= scf;
                }
            }
#pragma unroll
            for (int ne = 0; ne < 4; ++ne)
#pragma unroll
                for (int r = 0; r < 4; ++r) {
                    float p = __builtin_amdgcn_exp2f((sf[ne][r] - Mr[r]) * cexp);
                    Lp[r] += p;
                    Ps[wave][(lhi * 4 + r) * 72 + ne * 16 + l15] = (bf16)p;
                }

            // ---- O += P @ V from Vs[cur] ----
#pragma unroll
            for (int ks = 0; ks < 2; ++ks) {
                bf16x8 pa = *reinterpret_cast<const bf16x8*>(
                    &Ps[wave][l15 * 72 + ks * 32 + 8 * lhi]);
#pragma unroll
                for (int nf = 0; nf < 8; ++nf) {
                    int row = nf * 16 + l15;
                    bf16x8 vb = *reinterpret_cast<const bf16x8*>(
                        (const char*)Vs[cur] + ((row * 128 + (ks * 4 + lhi) * 16) ^ ((row & 7) << 4)));
                    oacc[nf] = __builtin_amdgcn_mfma_f32_16x16x32_bf16(pa, vb, oacc[nf], 0, 0, 0);
                }
            }

            // drain this iter's staged loads; one barrier per iter
            asm volatile("s_waitcnt vmcnt(0)" ::: "memory");
            __builtin_amdgcn_s_barrier();
        }

        // ---- final L reduce + epilogue: write [B*S][H] bf16 ----
#pragma unroll
        for (int m = 1; m < 16; m <<= 1)
#pragma unroll
            for (int r = 0; r < 4; ++r)
                Lp[r] += __shfl_xor(Lp[r], m);
        float inv[4];
#pragma unroll
        for (int r = 0; r < 4; ++r) inv[r] = 1.f / Lp[r];
#pragma unroll
        for (int nf = 0; nf < 8; ++nf)
#pragma unroll
            for (int r = 0; r < 4; ++r) {
                int s = qw + lhi * 4 + r;
                int d = nf * 16 + l15;
                Ob[((size_t)(b * SS + s)) * HH + h * HD + d] = (bf16)(oacc[nf][r] * inv[r]);
            }
    }
}

// ---------------------------------------------------------------------------
extern "C" void kernel_launch(void* const* d_in, const int* in_sizes, int n_in,
                              void* d_out, int out_size, void* d_ws, size_t ws_size,
                              hipStream_t stream) {
    const float* hs   = (const float*)d_in[0];
    const float* cosT = (const float*)d_in[2];
    const float* sinT = (const float*)d_in[3];
    const float* Wq   = (const float*)d_in[4];
    const float* Wk   = (const float*)d_in[5];
    const float* Wv   = (const float*)d_in[6];
    const float* Wo   = (const float*)d_in[7];
    float* out = (float*)d_out;

    char* w = (char*)d_ws;
    auto alloc = [&](size_t bytes) {
        char* p = w;
        w += (bytes + 255) & ~(size_t)255;
        return p;
    };
    const size_t XE = (size_t)BB * SS * HH;
    const size_t WE = (size_t)HH * HH;
    bf16* Xb   = (bf16*)alloc(XE * 2);
    bf16* Wqkv = (bf16*)alloc(3 * WE * 2);
    bf16* Wob  = (bf16*)alloc(WE * 2);
    bf16* QKV  = (bf16*)alloc(3 * XE * 2);
    bf16* Vtg  = (bf16*)alloc(XE * 2);
    bf16* Ob   = (bf16*)alloc(XE * 2);

    const int M = BB * SS;  // 4096
    bf16* Qh = QKV;
    bf16* Kh = QKV + XE;
    bf16* Vh = QKV + 2 * XE;

    {
        int total4 = (int)((XE + 4 * WE) / 4);
        cast_all<<<(total4 + 255) / 256, 256, 0, stream>>>(hs, Wq, Wk, Wv, Wo, Xb, Wqkv, Wob);
    }

    // fused QKV projection: M=4096, N=6144, K=2048, 256^2 8-phase, n-major XCD
    gemm256_qkv<<<dim3((M / 256) * (3 * HH / 256)), 512, 0, stream>>>(Xb, Wqkv, QKV, M, 3 * HH, HH);

    // merged RoPE (Q,K) + V transpose
    rope_tv<<<4096, 256, 0, stream>>>(Qh, Kh, cosT, sinT, Vh, Vtg);

    // attention: 256 blocks x 512 threads
    attn_kernel<<<256, 512, 0, stream>>>(Qh, Kh, Vtg, Ob);

    // out projection: M=4096, N=2048, K=2048, 2D grid
    dim3 ogrid(HH / 128, M / 128);
    gemm_bt<<<ogrid, 256, 0, stream>>>(Ob, Wob, out, M, HH, HH);
}